// Round 9
// baseline (1763.498 us; speedup 1.0000x reference)
//
#include <hip/hip_runtime.h>
#include <hip/hip_bf16.h>

#define N_NODES   50000
#define N_PAD     50048                 // ceil64
#define N_EDGES   800000
#define N_REL     16
#define N_GRAPHS  64
#define DIM       128
#define FC_DIM    256
#define N_CLASSES 16

#define NBINS     (N_REL * N_PAD)       // 800768 = 782*1024, key = rel*N_PAD+dst
#define NBLK_SCAN 782
#define NBLK      782                   // N_PAD/64
#define POOL_CH   64
#define QSTR      132                   // f32 elems per Q row (pad 128->132)

// ---- ws layout (bytes) ----
#define WS_HIST   0                     // 3203072 } contiguous
#define WS_HG     3203072               // 32768   } memset
#define WS_CNT    3235840               // 256     } region
#define MEMSET_SZ 3236096
#define WS_OFFS   3236096               // (NBINS+1)*4 -> pad 3203328
#define WS_CUR    6439424               // 3203072
#define WS_PART   9642496               // 4096
#define WS_SRCS   9646592               // 3200000
#define WS_X1     12846592              // 12812288
#define WS_X2     25658880              // 12812288
#define WS_AGG2   38471168              // f32: 25624576
#define WS_WB     64095744              // 1114112 -> end 65209856

typedef __attribute__((ext_vector_type(8))) short bf16x8;
typedef __attribute__((ext_vector_type(4))) float f32x4;

__device__ __forceinline__ void atomAddF(float* p, float v) {
#if defined(__gfx90a__) || defined(__gfx942__) || defined(__gfx950__)
    unsafeAtomicAdd(p, v);
#else
    atomicAdd(p, v);
#endif
}
__device__ __forceinline__ void ldsAdd(float* p, float v) {
    __hip_atomic_fetch_add(p, v, __ATOMIC_RELAXED, __HIP_MEMORY_SCOPE_WORKGROUP);
}

__device__ __forceinline__ float bf2f(unsigned int u) {
    union { float f; unsigned int i; } x; x.i = u << 16; return x.f;
}
__device__ __forceinline__ unsigned short f2bf(float f) {
    union { float f; unsigned int u; } x; x.f = f;
    unsigned int r = x.u + 0x7fff + ((x.u >> 16) & 1);
    return (unsigned short)(r >> 16);
}
// pack two f32 into packed bf16 pair (round-half-up) via byte-perm
__device__ __forceinline__ unsigned int bfpack(float a, float b) {
    unsigned int ua = __float_as_uint(a) + 0x8000u;
    unsigned int ub = __float_as_uint(b) + 0x8000u;
    return __builtin_amdgcn_perm(ub, ua, 0x07060302u);
}

__global__ void k_convX(const float* __restrict__ h, unsigned short* __restrict__ x1) {
    int i = blockIdx.x * blockDim.x + threadIdx.x;      // over N_PAD*DIM
    int v = i >> 7;
    x1[i] = (v < N_NODES) ? f2bf(h[i]) : (unsigned short)0;
}

// Wb[l][r][n][k] = bf16(W_l[r][k][n]); r==16 -> Ws_l
__global__ void k_convW(const float* __restrict__ W1, const float* __restrict__ Ws1,
                        const float* __restrict__ W2, const float* __restrict__ Ws2,
                        unsigned short* __restrict__ Wb) {
    int id = blockIdx.x * blockDim.x + threadIdx.x;     // 2*17*16384
    int l = id / 278528, rem = id % 278528;
    int r = rem >> 14, rr = rem & 16383;
    int n = rr >> 7, k = rr & 127;
    const float* W  = l ? W2 : W1;
    const float* Ws = l ? Ws2 : Ws1;
    float v = (r < 16) ? W[r * 16384 + k * 128 + n] : Ws[k * 128 + n];
    Wb[id] = f2bf(v);
}

__global__ void k_histK(const int* __restrict__ dst, const int* __restrict__ rel,
                        int* __restrict__ hist) {
    int e = blockIdx.x * blockDim.x + threadIdx.x;
    if (e < N_EDGES) atomicAdd(&hist[rel[e] * N_PAD + dst[e]], 1);
}

__global__ void k_scanA(const int* __restrict__ hist, int* __restrict__ partials) {
    __shared__ int red[256];
    int b = blockIdx.x, t = threadIdx.x;
    int4 v = ((const int4*)(hist + b * 1024))[t];
    red[t] = v.x + v.y + v.z + v.w;
    __syncthreads();
    for (int o = 128; o > 0; o >>= 1) {
        if (t < o) red[t] += red[t + o];
        __syncthreads();
    }
    if (t == 0) partials[b] = red[0];
}

__global__ void k_scanB(int* __restrict__ partials, int* __restrict__ offs_tail) {
    __shared__ int s1[256], s2[256];
    int t = threadIdx.x;
    int v[4]; int sum = 0;
    #pragma unroll
    for (int i = 0; i < 4; ++i) {
        int j = t * 4 + i;
        v[i] = (j < NBLK_SCAN) ? partials[j] : 0;
        sum += v[i];
    }
    s1[t] = sum; __syncthreads();
    int* cur = s1; int* nxt = s2;
    for (int o = 1; o < 256; o <<= 1) {
        nxt[t] = cur[t] + ((t >= o) ? cur[t - o] : 0);
        __syncthreads();
        int* tmp = cur; cur = nxt; nxt = tmp;
    }
    int run = cur[t] - sum;
    #pragma unroll
    for (int i = 0; i < 4; ++i) {
        int j = t * 4 + i;
        if (j < NBLK_SCAN) partials[j] = run;
        run += v[i];
    }
    if (t == 255) offs_tail[0] = cur[255];
}

__global__ void k_scanC(const int* __restrict__ hist, const int* __restrict__ partials,
                        int* __restrict__ offs, int* __restrict__ curp) {
    __shared__ int s1[256], s2[256];
    int b = blockIdx.x, t = threadIdx.x;
    int4 v = ((const int4*)(hist + b * 1024))[t];
    int sum = v.x + v.y + v.z + v.w;
    s1[t] = sum; __syncthreads();
    int* cur = s1; int* nxt = s2;
    for (int o = 1; o < 256; o <<= 1) {
        nxt[t] = cur[t] + ((t >= o) ? cur[t - o] : 0);
        __syncthreads();
        int* tmp = cur; cur = nxt; nxt = tmp;
    }
    int base = partials[b] + cur[t] - sum;
    int4 w;
    w.x = base;
    w.y = base + v.x;
    w.z = w.y + v.y;
    w.w = w.z + v.z;
    ((int4*)(offs + b * 1024))[t] = w;
    ((int4*)(curp + b * 1024))[t] = w;
}

// payload: (dstLocal<<16) | src   (src < 50000 < 2^16)
__global__ void k_scatterK(const int* __restrict__ src, const int* __restrict__ dst,
                           const int* __restrict__ rel, int* __restrict__ cur,
                           unsigned int* __restrict__ recs) {
    int e = blockIdx.x * blockDim.x + threadIdx.x;
    if (e < N_EDGES) {
        int d = dst[e];
        int pos = atomicAdd(&cur[rel[e] * N_PAD + d], 1);
        recs[pos] = ((unsigned int)(d & 63) << 16) | (unsigned int)src[e];
    }
}

// ---- fused RGCN layer: parallel ds_add_f32 segment-sum + MFMA ----
// Block = 64 dsts. Per rel: cnt*16 independent tasks (1 task = one 16B chunk of
// one edge's source row -> 8 ds_add_f32 into Q[dstLoc]). 16 lanes cover a row
// coalesced. Then Q(f32) -> bf16 A-frags -> MFMA against W[r] (B col-split by wave).
__global__ __launch_bounds__(256, 3) void k_layer(
    const unsigned short* __restrict__ x, const unsigned short* __restrict__ Wb,
    const int* __restrict__ offs, const unsigned int* __restrict__ recs,
    const float* __restrict__ bias,
    unsigned short* __restrict__ out_bf16, float* __restrict__ out_f32)
{
    __shared__ float Q[64 * QSTR];                 // 33792 B, f32 accum
    __shared__ int sBnd[16 * 65];                  // 4160 B

    int tid = threadIdx.x;
    int v0 = blockIdx.x * 64;
    int w = tid >> 6, l = tid & 63;
    int nl = l & 15, q = l >> 4;

    for (int i = tid; i < 16 * 65; i += 256) {
        int r = i / 65, d = i - r * 65;
        sBnd[i] = offs[r * N_PAD + v0 + d];
    }
    for (int i = tid; i < 64 * QSTR / 4; i += 256)
        ((float4*)Q)[i] = make_float4(0.f, 0.f, 0.f, 0.f);
    __syncthreads();

    f32x4 acc[4][2];
    #pragma unroll
    for (int m = 0; m < 4; ++m) {
        acc[m][0] = (f32x4){0.f, 0.f, 0.f, 0.f};
        acc[m][1] = (f32x4){0.f, 0.f, 0.f, 0.f};
    }

    for (int r = 0; r < 17; ++r) {
        // ---- B fragments for rel r (global, L2-resident; issued early) ----
        bf16x8 Bf[2][4];
        {
            const unsigned short* wr = Wb + r * 16384;
            #pragma unroll
            for (int nt = 0; nt < 2; ++nt) {
                int n = w * 32 + nt * 16 + nl;
                #pragma unroll
                for (int kc = 0; kc < 4; ++kc)
                    Bf[nt][kc] = *(const bf16x8*)(wr + n * 128 + kc * 32 + q * 8);
            }
        }
        // ---- build Q: fully parallel gather + LDS f32 atomic accumulate ----
        if (r < 16) {
            int segBeg = sBnd[r * 65], segEnd = sBnd[r * 65 + 64];
            int ntask = (segEnd - segBeg) << 4;
            for (int t = tid; t < ntask; t += 256) {
                unsigned int rec = recs[segBeg + (t >> 4)];
                int c = t & 15;
                const uint4 u = *(const uint4*)(x + (rec & 0xffffu) * DIM + c * 8);
                float* qp = Q + ((rec >> 16) & 63u) * QSTR + c * 8;
                ldsAdd(qp + 0, bf2f(u.x & 0xffff)); ldsAdd(qp + 1, bf2f(u.x >> 16));
                ldsAdd(qp + 2, bf2f(u.y & 0xffff)); ldsAdd(qp + 3, bf2f(u.y >> 16));
                ldsAdd(qp + 4, bf2f(u.z & 0xffff)); ldsAdd(qp + 5, bf2f(u.z >> 16));
                ldsAdd(qp + 6, bf2f(u.w & 0xffff)); ldsAdd(qp + 7, bf2f(u.w >> 16));
            }
        } else {                                   // self-loop: exclusive writes
            for (int t = tid; t < 1024; t += 256) {
                int e = t >> 4, c = t & 15;
                const uint4 u = *(const uint4*)(x + (v0 + e) * DIM + c * 8);
                float* qp = Q + e * QSTR + c * 8;
                qp[0] = bf2f(u.x & 0xffff); qp[1] = bf2f(u.x >> 16);
                qp[2] = bf2f(u.y & 0xffff); qp[3] = bf2f(u.y >> 16);
                qp[4] = bf2f(u.z & 0xffff); qp[5] = bf2f(u.z >> 16);
                qp[6] = bf2f(u.w & 0xffff); qp[7] = bf2f(u.w >> 16);
            }
        }
        __syncthreads();                           // Q ready

        // ---- MFMA: A from Q (f32 -> bf16 via perm-pack) ----
        #pragma unroll
        for (int kc = 0; kc < 4; ++kc) {
            #pragma unroll
            for (int m = 0; m < 4; ++m) {
                const float* qrow = Q + (m * 16 + nl) * QSTR + kc * 32 + q * 8;
                f32x4 qa = *(const f32x4*)qrow;
                f32x4 qb = *(const f32x4*)(qrow + 4);
                union { unsigned int u[4]; bf16x8 v; } au;
                au.u[0] = bfpack(qa[0], qa[1]);
                au.u[1] = bfpack(qa[2], qa[3]);
                au.u[2] = bfpack(qb[0], qb[1]);
                au.u[3] = bfpack(qb[2], qb[3]);
                acc[m][0] = __builtin_amdgcn_mfma_f32_16x16x32_bf16(au.v, Bf[0][kc], acc[m][0], 0, 0, 0);
                acc[m][1] = __builtin_amdgcn_mfma_f32_16x16x32_bf16(au.v, Bf[1][kc], acc[m][1], 0, 0, 0);
            }
        }
        __syncthreads();                           // all waves done reading Q

        if (r < 16) {                              // re-zero for next rel
            for (int i = tid; i < 64 * QSTR / 4; i += 256)
                ((float4*)Q)[i] = make_float4(0.f, 0.f, 0.f, 0.f);
            __syncthreads();
        }
    }

    // ---- epilogue: C layout col=lane&15, row=q*4+reg ----
    #pragma unroll
    for (int m = 0; m < 4; ++m) {
        #pragma unroll
        for (int nt = 0; nt < 2; ++nt) {
            int col = w * 32 + nt * 16 + nl;
            float bv = bias[col];
            #pragma unroll
            for (int reg = 0; reg < 4; ++reg) {
                int node = v0 + m * 16 + q * 4 + reg;
                float val = acc[m][nt][reg] + bv;
                if (out_bf16) out_bf16[node * 128 + col] = f2bf(fmaxf(val, 0.f));
                else          out_f32[node * 128 + col]  = val;
            }
        }
    }
}

__global__ void k_pool(const float* __restrict__ agg2, const int* __restrict__ gids,
                       float* __restrict__ hg_sum, int* __restrict__ cnt)
{
    int d  = threadIdx.x;                    // 128
    int n0 = blockIdx.x * POOL_CH;
    int nend = min(n0 + POOL_CH, N_NODES);
    int curg = gids[n0];
    float run = 0.f;
    for (int n = n0; n < nend; ++n) {
        int g = gids[n];
        if (g != curg) { atomAddF(&hg_sum[curg*DIM + d], run); run = 0.f; curg = g; }
        run += fmaxf(agg2[n*DIM + d], 0.f);
    }
    atomAddF(&hg_sum[curg*DIM + d], run);
    if (d == 0) {
        int cg = gids[n0]; int rl = 0;
        for (int n = n0; n < nend; ++n) {
            int g = gids[n];
            if (g != cg) { atomicAdd(&cnt[cg], rl); rl = 0; cg = g; }
            rl++;
        }
        atomicAdd(&cnt[cg], rl);
    }
}

__global__ __launch_bounds__(256) void k_head(
    const float* __restrict__ hg_sum, const int* __restrict__ cnt,
    const float* __restrict__ Wfc, const float* __restrict__ bfc,
    const float* __restrict__ Wc, const float* __restrict__ bc,
    float* __restrict__ out)
{
    int g = blockIdx.x, t = threadIdx.x;
    __shared__ float hgl[DIM];
    __shared__ float fcl[FC_DIM];
    __shared__ float lg[N_CLASSES];
    if (t < DIM) {
        float c = (float)max(cnt[g], 1);
        hgl[t] = hg_sum[g*DIM + t] / c;
    }
    __syncthreads();
    {
        float sv = bfc[t];
        #pragma unroll 4
        for (int k = 0; k < DIM; ++k) sv += hgl[k] * Wfc[k*FC_DIM + t];
        fcl[t] = fmaxf(sv, 0.f);
    }
    __syncthreads();
    if (t < N_CLASSES) {
        float lgt = bc[t];
        #pragma unroll 4
        for (int k = 0; k < FC_DIM; ++k) lgt += fcl[k] * Wc[k*N_CLASSES + t];
        lg[t] = lgt;
    }
    __syncthreads();
    if (t < N_CLASSES) {
        float m = lg[0];
        #pragma unroll
        for (int c = 1; c < N_CLASSES; ++c) m = fmaxf(m, lg[c]);
        float sden = 0.f;
        #pragma unroll
        for (int c = 0; c < N_CLASSES; ++c) sden += expf(lg[c] - m);
        out[g*N_CLASSES + t] = expf(lg[t] - m) / sden;
    }
}

extern "C" void kernel_launch(void* const* d_in, const int* in_sizes, int n_in,
                              void* d_out, int out_size, void* d_ws, size_t ws_size,
                              hipStream_t stream)
{
    const float* h   = (const float*)d_in[0];
    const int*   src = (const int*)d_in[1];
    const int*   dst = (const int*)d_in[2];
    const int*   rel = (const int*)d_in[3];
    const int*   gid = (const int*)d_in[4];
    const float* W1  = (const float*)d_in[5];
    const float* Ws1 = (const float*)d_in[6];
    const float* b1  = (const float*)d_in[7];
    const float* W2  = (const float*)d_in[8];
    const float* Ws2 = (const float*)d_in[9];
    const float* b2  = (const float*)d_in[10];
    const float* Wfc = (const float*)d_in[11];
    const float* bfc = (const float*)d_in[12];
    const float* Wc  = (const float*)d_in[13];
    const float* bc  = (const float*)d_in[14];
    float* out = (float*)d_out;

    char* ws = (char*)d_ws;
    int*   hist  = (int*)(ws + WS_HIST);
    float* hgsum = (float*)(ws + WS_HG);
    int*   cnt   = (int*)(ws + WS_CNT);
    int*   offs  = (int*)(ws + WS_OFFS);
    int*   cur   = (int*)(ws + WS_CUR);
    int*   part  = (int*)(ws + WS_PART);
    unsigned int* recs = (unsigned int*)(ws + WS_SRCS);
    unsigned short* x1  = (unsigned short*)(ws + WS_X1);
    unsigned short* x2  = (unsigned short*)(ws + WS_X2);
    float* agg2  = (float*)(ws + WS_AGG2);
    unsigned short* Wb  = (unsigned short*)(ws + WS_WB);

    hipMemsetAsync(hist, 0, MEMSET_SZ, stream);   // hist + hgsum + cnt contiguous

    k_convX<<<(N_PAD * DIM) / 256, 256, 0, stream>>>(h, x1);
    k_convW<<<(2 * 17 * 16384) / 256, 256, 0, stream>>>(W1, Ws1, W2, Ws2, Wb);

    k_histK<<<(N_EDGES + 255) / 256, 256, 0, stream>>>(dst, rel, hist);
    k_scanA<<<NBLK_SCAN, 256, 0, stream>>>(hist, part);
    k_scanB<<<1, 256, 0, stream>>>(part, offs + NBINS);
    k_scanC<<<NBLK_SCAN, 256, 0, stream>>>(hist, part, offs, cur);
    k_scatterK<<<(N_EDGES + 255) / 256, 256, 0, stream>>>(src, dst, rel, cur, recs);

    k_layer<<<NBLK, 256, 0, stream>>>(x1, Wb, offs, recs, b1, x2, nullptr);
    k_layer<<<NBLK, 256, 0, stream>>>(x2, Wb + 17 * 16384, offs, recs, b2, nullptr, agg2);

    k_pool<<<NBLK, 128, 0, stream>>>(agg2, gid, hgsum, cnt);
    k_head<<<N_GRAPHS, 256, 0, stream>>>(hgsum, cnt, Wfc, bfc, Wc, bc, out);
}

// Round 11
// 500.166 us; speedup vs baseline: 3.5258x; 3.5258x over previous
//
#include <hip/hip_runtime.h>
#include <hip/hip_bf16.h>

#define N_NODES   50000
#define N_PAD     50048                 // ceil64 (= 391*128)
#define N_EDGES   800000
#define N_REL     16
#define N_GRAPHS  64
#define DIM       128
#define FC_DIM    256
#define N_CLASSES 16

#define NBINS_D   50176                 // dst bins padded to 49*1024
#define NBLK_SCAN 49
#define NBLK_B    782                   // N_PAD/64
#define POOL_CH   64
#define GRP_A     6

// ---- ws layout (bytes) ----
#define WS_HIST   0                     // 50176*4 = 200704 } contiguous
#define WS_HG     200704                // 32768            } memset
#define WS_CNT    233472                // 256              } region
#define MEMSET_SZ 233728
#define WS_OFFS   233728                // 50208*4 = 200832
#define WS_CUR    434560                // 200704
#define WS_PART   635264                // 256
#define WS_SRCS   635520                // 800000*4 = 3200000
#define WS_X1     3835520               // 50048*128*2 = 12812288
#define WS_X2     16647808              // 12812288
#define WS_AGG    29460096              // bf16 agg: 12812288
#define WS_WB     42272384              // 2*17*128*128*2 = 1114112
#define WS_T      43386496              // + slots * SLOT_BYTES
#define SLOT_BYTES 12812288ull          // N_PAD*128*2

#define XW_TOTAL  (N_PAD * DIM + 2 * 17 * 16384)   // 6963200, /256 = 27200

typedef __attribute__((ext_vector_type(8))) short bf16x8;
typedef __attribute__((ext_vector_type(4))) float f32x4;

__device__ __forceinline__ void atomAddF(float* p, float v) {
#if defined(__gfx90a__) || defined(__gfx942__) || defined(__gfx950__)
    unsafeAtomicAdd(p, v);
#else
    atomicAdd(p, v);
#endif
}

__device__ __forceinline__ float bf2f(unsigned int u) {
    union { float f; unsigned int i; } x; x.i = u << 16; return x.f;
}
__device__ __forceinline__ unsigned short f2bf(float f) {
    union { float f; unsigned int u; } x; x.f = f;
    unsigned int r = x.u + 0x7fff + ((x.u >> 16) & 1);
    return (unsigned short)(r >> 16);
}
__device__ __forceinline__ void accum8(float* qa, uint4 u) {
    qa[0] += bf2f(u.x & 0xffff); qa[1] += bf2f(u.x >> 16);
    qa[2] += bf2f(u.y & 0xffff); qa[3] += bf2f(u.y >> 16);
    qa[4] += bf2f(u.z & 0xffff); qa[5] += bf2f(u.z >> 16);
    qa[6] += bf2f(u.w & 0xffff); qa[7] += bf2f(u.w >> 16);
}
__device__ __forceinline__ void pack16(const float* qa, unsigned short* dst) {
    #pragma unroll
    for (int j = 0; j < 2; ++j) {
        uint4 w;
        w.x = ((unsigned int)f2bf(qa[j*8+1]) << 16) | f2bf(qa[j*8+0]);
        w.y = ((unsigned int)f2bf(qa[j*8+3]) << 16) | f2bf(qa[j*8+2]);
        w.z = ((unsigned int)f2bf(qa[j*8+5]) << 16) | f2bf(qa[j*8+4]);
        w.w = ((unsigned int)f2bf(qa[j*8+7]) << 16) | f2bf(qa[j*8+6]);
        ((uint4*)dst)[j] = w;
    }
}

// merged convX + convW: one launch
__global__ void k_convXW(const float* __restrict__ h, unsigned short* __restrict__ x1,
                         const float* __restrict__ W1, const float* __restrict__ Ws1,
                         const float* __restrict__ W2, const float* __restrict__ Ws2,
                         unsigned short* __restrict__ Wb) {
    int id = blockIdx.x * blockDim.x + threadIdx.x;
    if (id < N_PAD * DIM) {
        int v = id >> 7;
        x1[id] = (v < N_NODES) ? f2bf(h[id]) : (unsigned short)0;
    } else {
        int t = id - N_PAD * DIM;                       // 0 .. 2*278528-1
        int l = t / 278528, rem = t % 278528;
        int r = rem >> 14, rr = rem & 16383;
        int n = rr >> 7, k = rr & 127;
        const float* W  = l ? W2 : W1;
        const float* Ws = l ? Ws2 : Ws1;
        float v = (r < 16) ? W[r * 16384 + k * 128 + n] : Ws[k * 128 + n];
        Wb[t] = f2bf(v);
    }
}

__global__ void k_histK(const int* __restrict__ dst, int* __restrict__ hist) {
    int e = blockIdx.x * blockDim.x + threadIdx.x;
    if (e < N_EDGES) atomicAdd(&hist[dst[e]], 1);
}

__global__ void k_scanA(const int* __restrict__ hist, int* __restrict__ partials) {
    __shared__ int red[256];
    int b = blockIdx.x, t = threadIdx.x;
    int4 v = ((const int4*)(hist + b * 1024))[t];
    red[t] = v.x + v.y + v.z + v.w;
    __syncthreads();
    for (int o = 128; o > 0; o >>= 1) {
        if (t < o) red[t] += red[t + o];
        __syncthreads();
    }
    if (t == 0) partials[b] = red[0];
}

__global__ void k_scanB(int* __restrict__ partials, int* __restrict__ offs_tail) {
    __shared__ int s1[256], s2[256];
    int t = threadIdx.x;
    int v[4]; int sum = 0;
    #pragma unroll
    for (int i = 0; i < 4; ++i) {
        int j = t * 4 + i;
        v[i] = (j < NBLK_SCAN) ? partials[j] : 0;
        sum += v[i];
    }
    s1[t] = sum; __syncthreads();
    int* cur = s1; int* nxt = s2;
    for (int o = 1; o < 256; o <<= 1) {
        nxt[t] = cur[t] + ((t >= o) ? cur[t - o] : 0);
        __syncthreads();
        int* tmp = cur; cur = nxt; nxt = tmp;
    }
    int run = cur[t] - sum;
    #pragma unroll
    for (int i = 0; i < 4; ++i) {
        int j = t * 4 + i;
        if (j < NBLK_SCAN) partials[j] = run;
        run += v[i];
    }
    if (t == 255) offs_tail[0] = cur[255];
}

__global__ void k_scanC(const int* __restrict__ hist, const int* __restrict__ partials,
                        int* __restrict__ offs, int* __restrict__ curp) {
    __shared__ int s1[256], s2[256];
    int b = blockIdx.x, t = threadIdx.x;
    int4 v = ((const int4*)(hist + b * 1024))[t];
    int sum = v.x + v.y + v.z + v.w;
    s1[t] = sum; __syncthreads();
    int* cur = s1; int* nxt = s2;
    for (int o = 1; o < 256; o <<= 1) {
        nxt[t] = cur[t] + ((t >= o) ? cur[t - o] : 0);
        __syncthreads();
        int* tmp = cur; cur = nxt; nxt = tmp;
    }
    int base = partials[b] + cur[t] - sum;
    int4 w;
    w.x = base;
    w.y = base + v.x;
    w.z = w.y + v.y;
    w.w = w.z + v.z;
    ((int4*)(offs + b * 1024))[t] = w;
    ((int4*)(curp + b * 1024))[t] = w;
}

__global__ void k_scatterK(const int* __restrict__ src, const int* __restrict__ dst,
                           const int* __restrict__ rel, int* __restrict__ cur,
                           unsigned int* __restrict__ srcs) {
    int e = blockIdx.x * blockDim.x + threadIdx.x;
    if (e < N_EDGES) {
        int pos = atomicAdd(&cur[dst[e]], 1);
        srcs[pos] = ((unsigned int)rel[e] << 16) | (unsigned int)src[e];
    }
}

// ---- Phase A v3: X tile staged once; C staged in LDS -> coalesced dwordx4 T stores ----
__global__ __launch_bounds__(256) void k_phaseA(
    const unsigned short* __restrict__ x, const unsigned short* __restrict__ Wb,
    unsigned short* __restrict__ T, int r0, int cnt)
{
    __shared__ unsigned short Xs[64 * 136];              // 17408 B
    __shared__ unsigned short Cs[64 * 136];              // 17408 B (C staging)

    int tid = threadIdx.x;
    int v0 = blockIdx.x * 64;
    int rbase = r0 + blockIdx.y * GRP_A;
    int w = tid >> 6, l = tid & 63;
    int nl = l & 15, q = l >> 4;

    {   // stage X tile: 4 threads/row, 4 uint4 each
        int row = tid >> 2, c0 = tid & 3;
        const uint4* xp = (const uint4*)(x + (v0 + row) * 128);
        uint4* lp = (uint4*)(&Xs[row * 136]);
        #pragma unroll
        for (int i = 0; i < 4; ++i) lp[c0 + 4 * i] = xp[c0 + 4 * i];
    }
    __syncthreads();

    int rend = rbase + GRP_A;
    if (rend > r0 + cnt) rend = r0 + cnt;
    for (int rel = rbase; rel < rend; ++rel) {
        bf16x8 Bf[2][4];
        const unsigned short* wr = Wb + rel * 16384;
        #pragma unroll
        for (int nt = 0; nt < 2; ++nt) {
            int n = w * 32 + nt * 16 + nl;
            #pragma unroll
            for (int kc = 0; kc < 4; ++kc)
                Bf[nt][kc] = *(const bf16x8*)(wr + n * 128 + kc * 32 + q * 8);
        }
        #pragma unroll
        for (int m = 0; m < 4; ++m) {
            f32x4 a0 = {0.f,0.f,0.f,0.f}, a1 = {0.f,0.f,0.f,0.f};
            #pragma unroll
            for (int kc = 0; kc < 4; ++kc) {
                bf16x8 a = *(const bf16x8*)(&Xs[(m * 16 + nl) * 136 + kc * 32 + q * 8]);
                a0 = __builtin_amdgcn_mfma_f32_16x16x32_bf16(a, Bf[0][kc], a0, 0, 0, 0);
                a1 = __builtin_amdgcn_mfma_f32_16x16x32_bf16(a, Bf[1][kc], a1, 0, 0, 0);
            }
            int col = w * 32 + nl;                       // C: col=lane&15, row=q*4+reg
            #pragma unroll
            for (int reg = 0; reg < 4; ++reg) {
                int row = m * 16 + q * 4 + reg;
                Cs[row * 136 + col]      = f2bf(a0[reg]);
                Cs[row * 136 + col + 16] = f2bf(a1[reg]);
            }
        }
        __syncthreads();                                 // Cs complete
        {   // cooperative coalesced store: 64 rows x 16 uint4 = 1024 chunks, 4/thread
            unsigned short* Tb = T + (size_t)(rel - r0) * (N_PAD * DIM) + (size_t)v0 * DIM;
            #pragma unroll
            for (int it = 0; it < 4; ++it) {
                int c = tid + it * 256;                  // 0..1023
                int row = c >> 4, k8 = c & 15;
                uint4 vv = *(const uint4*)(&Cs[row * 136 + k8 * 8]);
                *(uint4*)(Tb + row * DIM + k8 * 8) = vv;
            }
        }
        __syncthreads();                                 // Cs free for next rel
    }
}

// ---- Phase B: 32 dsts/block, 8 lanes/dst, 4-way unrolled T-row stream ----
__global__ __launch_bounds__(256) void k_phaseB(
    const unsigned short* __restrict__ T, const unsigned int* __restrict__ srcs,
    const int* __restrict__ offs, unsigned short* __restrict__ agg,
    const float* __restrict__ bias, int r0, int cntR, int first,
    unsigned short* __restrict__ out_relu)
{
    __shared__ int sOffs[33];
    __shared__ float sBias[128];
    int tid = threadIdx.x;
    int v0 = blockIdx.x * 32;
    if (tid < 33) sOffs[tid] = offs[v0 + tid];
    if (tid >= 64 && tid < 96) ((float4*)sBias)[tid - 64] = ((const float4*)bias)[tid - 64];
    __syncthreads();

    int g = tid >> 3, s = tid & 7;
    int dst = v0 + g;
    float qa[16];
    #pragma unroll
    for (int i = 0; i < 16; ++i) qa[i] = 0.f;
    if (first) {
        #pragma unroll
        for (int i = 0; i < 16; ++i) qa[i] = sBias[s * 16 + i];
    } else {
        const uint4* ap = (const uint4*)(agg + dst * DIM + s * 16);
        uint4 u0 = ap[0], u1 = ap[1];
        accum8(qa, u0); accum8(qa + 8, u1);
    }

    int beg = sOffs[g], end = sOffs[g + 1];
    int e = beg;
    for (; e + 3 < end; e += 4) {                        // 4-way unroll for MLP
        unsigned int r0v = srcs[e], r1v = srcs[e+1], r2v = srcs[e+2], r3v = srcs[e+3];
        unsigned int q0 = (r0v >> 16) - r0, q1 = (r1v >> 16) - r0;
        unsigned int q2 = (r2v >> 16) - r0, q3 = (r3v >> 16) - r0;
        if (q0 < (unsigned int)cntR) {
            const uint4* tp = (const uint4*)(T + ((size_t)q0 * (N_PAD * DIM)
                                                  + (r0v & 0xffffu) * DIM) + s * 16);
            uint4 u0 = tp[0], u1 = tp[1];
            accum8(qa, u0); accum8(qa + 8, u1);
        }
        if (q1 < (unsigned int)cntR) {
            const uint4* tp = (const uint4*)(T + ((size_t)q1 * (N_PAD * DIM)
                                                  + (r1v & 0xffffu) * DIM) + s * 16);
            uint4 u0 = tp[0], u1 = tp[1];
            accum8(qa, u0); accum8(qa + 8, u1);
        }
        if (q2 < (unsigned int)cntR) {
            const uint4* tp = (const uint4*)(T + ((size_t)q2 * (N_PAD * DIM)
                                                  + (r2v & 0xffffu) * DIM) + s * 16);
            uint4 u0 = tp[0], u1 = tp[1];
            accum8(qa, u0); accum8(qa + 8, u1);
        }
        if (q3 < (unsigned int)cntR) {
            const uint4* tp = (const uint4*)(T + ((size_t)q3 * (N_PAD * DIM)
                                                  + (r3v & 0xffffu) * DIM) + s * 16);
            uint4 u0 = tp[0], u1 = tp[1];
            accum8(qa, u0); accum8(qa + 8, u1);
        }
    }
    for (; e < end; ++e) {
        unsigned int rec = srcs[e];
        unsigned int qq = (rec >> 16) - r0;
        if (qq < (unsigned int)cntR) {
            const uint4* tp = (const uint4*)(T + ((size_t)qq * (N_PAD * DIM)
                                                  + (rec & 0xffffu) * DIM) + s * 16);
            uint4 u0 = tp[0], u1 = tp[1];
            accum8(qa, u0); accum8(qa + 8, u1);
        }
    }
    if (r0 + cntR == 17) {                               // self-loop slot in this pass
        const uint4* tp = (const uint4*)(T + ((size_t)(16 - r0) * (N_PAD * DIM)
                                              + (size_t)dst * DIM) + s * 16);
        uint4 u0 = tp[0], u1 = tp[1];
        accum8(qa, u0); accum8(qa + 8, u1);
    }

    if (out_relu) {                                      // final pass, layer-1: relu->x2
        float qr[16];
        #pragma unroll
        for (int i = 0; i < 16; ++i) qr[i] = fmaxf(qa[i], 0.f);
        pack16(qr, out_relu + dst * DIM + s * 16);
    } else {
        pack16(qa, agg + dst * DIM + s * 16);
    }
}

__global__ void k_pool(const unsigned short* __restrict__ agg2, const int* __restrict__ gids,
                       float* __restrict__ hg_sum, int* __restrict__ cnt)
{
    int d  = threadIdx.x;                    // 128
    int n0 = blockIdx.x * POOL_CH;
    int nend = min(n0 + POOL_CH, N_NODES);
    int curg = gids[n0];
    float run = 0.f;
    for (int n = n0; n < nend; ++n) {
        int g = gids[n];
        if (g != curg) { atomAddF(&hg_sum[curg*DIM + d], run); run = 0.f; curg = g; }
        run += fmaxf(bf2f((unsigned int)agg2[n*DIM + d]), 0.f);
    }
    atomAddF(&hg_sum[curg*DIM + d], run);
    if (d == 0) {
        int cg = gids[n0]; int rl = 0;
        for (int n = n0; n < nend; ++n) {
            int g = gids[n];
            if (g != cg) { atomicAdd(&cnt[cg], rl); rl = 0; cg = g; }
            rl++;
        }
        atomicAdd(&cnt[cg], rl);
    }
}

__global__ __launch_bounds__(256) void k_head(
    const float* __restrict__ hg_sum, const int* __restrict__ cnt,
    const float* __restrict__ Wfc, const float* __restrict__ bfc,
    const float* __restrict__ Wc, const float* __restrict__ bc,
    float* __restrict__ out)
{
    int g = blockIdx.x, t = threadIdx.x;
    __shared__ float hgl[DIM];
    __shared__ float fcl[FC_DIM];
    __shared__ float lg[N_CLASSES];
    if (t < DIM) {
        float c = (float)max(cnt[g], 1);
        hgl[t] = hg_sum[g*DIM + t] / c;
    }
    __syncthreads();
    {
        float sv = bfc[t];
        #pragma unroll 4
        for (int k = 0; k < DIM; ++k) sv += hgl[k] * Wfc[k*FC_DIM + t];
        fcl[t] = fmaxf(sv, 0.f);
    }
    __syncthreads();
    if (t < N_CLASSES) {
        float lgt = bc[t];
        #pragma unroll 4
        for (int k = 0; k < FC_DIM; ++k) lgt += fcl[k] * Wc[k*N_CLASSES + t];
        lg[t] = lgt;
    }
    __syncthreads();
    if (t < N_CLASSES) {
        float m = lg[0];
        #pragma unroll
        for (int c = 1; c < N_CLASSES; ++c) m = fmaxf(m, lg[c]);
        float sden = 0.f;
        #pragma unroll
        for (int c = 0; c < N_CLASSES; ++c) sden += expf(lg[c] - m);
        out[g*N_CLASSES + t] = expf(lg[t] - m) / sden;
    }
}

extern "C" void kernel_launch(void* const* d_in, const int* in_sizes, int n_in,
                              void* d_out, int out_size, void* d_ws, size_t ws_size,
                              hipStream_t stream)
{
    const float* h   = (const float*)d_in[0];
    const int*   src = (const int*)d_in[1];
    const int*   dst = (const int*)d_in[2];
    const int*   rel = (const int*)d_in[3];
    const int*   gid = (const int*)d_in[4];
    const float* W1  = (const float*)d_in[5];
    const float* Ws1 = (const float*)d_in[6];
    const float* b1  = (const float*)d_in[7];
    const float* W2  = (const float*)d_in[8];
    const float* Ws2 = (const float*)d_in[9];
    const float* b2  = (const float*)d_in[10];
    const float* Wfc = (const float*)d_in[11];
    const float* bfc = (const float*)d_in[12];
    const float* Wc  = (const float*)d_in[13];
    const float* bc  = (const float*)d_in[14];
    float* out = (float*)d_out;

    char* ws = (char*)d_ws;
    int*   hist  = (int*)(ws + WS_HIST);
    float* hgsum = (float*)(ws + WS_HG);
    int*   cnt   = (int*)(ws + WS_CNT);
    int*   offs  = (int*)(ws + WS_OFFS);
    int*   cur   = (int*)(ws + WS_CUR);
    int*   part  = (int*)(ws + WS_PART);
    unsigned int* srcs = (unsigned int*)(ws + WS_SRCS);
    unsigned short* x1  = (unsigned short*)(ws + WS_X1);
    unsigned short* x2  = (unsigned short*)(ws + WS_X2);
    unsigned short* agg = (unsigned short*)(ws + WS_AGG);
    unsigned short* Wb  = (unsigned short*)(ws + WS_WB);
    unsigned short* T   = (unsigned short*)(ws + WS_T);

    // how many rel-slots of T fit in ws (constant per harness -> capture-safe)
    int slots = 1;
    if (ws_size > (size_t)WS_T) {
        unsigned long long avail = (unsigned long long)ws_size - WS_T;
        slots = (int)(avail / SLOT_BYTES);
        if (slots > 17) slots = 17;
        if (slots < 1) slots = 1;
    }

    hipMemsetAsync(hist, 0, MEMSET_SZ, stream);

    k_convXW<<<XW_TOTAL / 256, 256, 0, stream>>>(h, x1, W1, Ws1, W2, Ws2, Wb);

    k_histK<<<(N_EDGES + 255) / 256, 256, 0, stream>>>(dst, hist);
    k_scanA<<<NBLK_SCAN, 256, 0, stream>>>(hist, part);
    k_scanB<<<1, 256, 0, stream>>>(part, offs + NBINS_D);
    k_scanC<<<NBLK_SCAN, 256, 0, stream>>>(hist, part, offs, cur);
    k_scatterK<<<(N_EDGES + 255) / 256, 256, 0, stream>>>(src, dst, rel, cur, srcs);

    for (int layer = 0; layer < 2; ++layer) {
        const unsigned short* xin = layer ? x2 : x1;
        const unsigned short* WbL = Wb + layer * 17 * 16384;
        const float* bL = layer ? b2 : b1;
        for (int r0 = 0; r0 < 17; r0 += slots) {
            int c = 17 - r0; if (c > slots) c = slots;
            int lastP = (r0 + c == 17);
            dim3 gA(NBLK_B, (c + GRP_A - 1) / GRP_A);
            k_phaseA<<<gA, 256, 0, stream>>>(xin, WbL, T, r0, c);
            k_phaseB<<<N_PAD / 32, 256, 0, stream>>>(T, srcs, offs, agg, bL, r0, c,
                                                     r0 == 0,
                                                     (layer == 0 && lastP) ? x2 : nullptr);
        }
    }

    k_pool<<<NBLK_B, 128, 0, stream>>>(agg, gid, hgsum, cnt);
    k_head<<<N_GRAPHS, 256, 0, stream>>>(hgsum, cnt, Wfc, bfc, Wc, bc, out);
}

// Round 12
// 497.572 us; speedup vs baseline: 3.5442x; 1.0052x over previous
//
#include <hip/hip_runtime.h>
#include <hip/hip_bf16.h>

#define N_NODES   50000
#define N_PAD     50048                 // ceil64
#define N_EDGES   800000
#define N_REL     16
#define N_GRAPHS  64
#define DIM       128
#define FC_DIM    256
#define N_CLASSES 16

#define SB        50176                 // src bins per rel (49*1024)
#define NBINS_P   (16 * SB)             // 802816, key = rel*SB + src
#define NBLK_PP   784
#define NBINS_D   50176                 // dst bins (49*1024)
#define NBLK_PD   49
#define POOL_CH   64
#define MAXBLK_A  13294                 // (16*50048 + 50048)/64 worst case

// ---- ws layout (bytes, 256-aligned) ----
#define WS_HISTP  0                     // 3211264 } contiguous
#define WS_HISTD  3211264               // 200704  } memset
#define WS_HG     3411968               // 32768   } region
#define WS_CNT    3444736               // 256     }
#define WS_SRCOF  3444992               // 3203072 } (pads must be 0)
#define MEMSET_SZ 6648064
#define WS_OFFSD  6648064               // 200960
#define WS_CURD   6849024               // 200704
#define WS_PARTD  7049728               // 256
#define WS_PARTP  7049984               // 3328
#define WS_BLKB   7053312               // 3328
#define WS_RELB   7056640               // 256 (relBase[0..16], [16]=RTOT)
#define WS_CIDMAP 7056896               // 3211264
#define WS_RECS   10268160              // 3200000
#define WS_X1     13468160              // 12812288
#define WS_X2     26280448              // 12812288
#define WS_AGG    39092736              // 12812288 (bf16)
#define WS_WB     51905024              // 1114112
#define WS_T      53019136              // + rows*256B (actual ~142MB)

#define XW_TOTAL  (N_PAD * DIM + 2 * 17 * 16384)   // 6963200

typedef __attribute__((ext_vector_type(8))) short bf16x8;
typedef __attribute__((ext_vector_type(4))) float f32x4;

__device__ __forceinline__ void atomAddF(float* p, float v) {
#if defined(__gfx90a__) || defined(__gfx942__) || defined(__gfx950__)
    unsafeAtomicAdd(p, v);
#else
    atomicAdd(p, v);
#endif
}

__device__ __forceinline__ float bf2f(unsigned int u) {
    union { float f; unsigned int i; } x; x.i = u << 16; return x.f;
}
__device__ __forceinline__ unsigned short f2bf(float f) {
    union { float f; unsigned int u; } x; x.f = f;
    unsigned int r = x.u + 0x7fff + ((x.u >> 16) & 1);
    return (unsigned short)(r >> 16);
}
__device__ __forceinline__ void accum8(float* qa, uint4 u) {
    qa[0] += bf2f(u.x & 0xffff); qa[1] += bf2f(u.x >> 16);
    qa[2] += bf2f(u.y & 0xffff); qa[3] += bf2f(u.y >> 16);
    qa[4] += bf2f(u.z & 0xffff); qa[5] += bf2f(u.z >> 16);
    qa[6] += bf2f(u.w & 0xffff); qa[7] += bf2f(u.w >> 16);
}
__device__ __forceinline__ void pack16(const float* qa, unsigned short* dst) {
    #pragma unroll
    for (int j = 0; j < 2; ++j) {
        uint4 w;
        w.x = ((unsigned int)f2bf(qa[j*8+1]) << 16) | f2bf(qa[j*8+0]);
        w.y = ((unsigned int)f2bf(qa[j*8+3]) << 16) | f2bf(qa[j*8+2]);
        w.z = ((unsigned int)f2bf(qa[j*8+5]) << 16) | f2bf(qa[j*8+4]);
        w.w = ((unsigned int)f2bf(qa[j*8+7]) << 16) | f2bf(qa[j*8+6]);
        ((uint4*)dst)[j] = w;
    }
}

// merged convX + convW
__global__ void k_convXW(const float* __restrict__ h, unsigned short* __restrict__ x1,
                         const float* __restrict__ W1, const float* __restrict__ Ws1,
                         const float* __restrict__ W2, const float* __restrict__ Ws2,
                         unsigned short* __restrict__ Wb) {
    int id = blockIdx.x * blockDim.x + threadIdx.x;
    if (id < N_PAD * DIM) {
        int v = id >> 7;
        x1[id] = (v < N_NODES) ? f2bf(h[id]) : (unsigned short)0;
    } else {
        int t = id - N_PAD * DIM;
        int l = t / 278528, rem = t % 278528;
        int r = rem >> 14, rr = rem & 16383;
        int n = rr >> 7, k = rr & 127;
        const float* W  = l ? W2 : W1;
        const float* Ws = l ? Ws2 : Ws1;
        float v = (r < 16) ? W[r * 16384 + k * 128 + n] : Ws[k * 128 + n];
        Wb[t] = f2bf(v);
    }
}

// both histograms in one pass
__global__ void k_hist2(const int* __restrict__ src, const int* __restrict__ dst,
                        const int* __restrict__ rel,
                        int* __restrict__ histP, int* __restrict__ histD) {
    int e = blockIdx.x * blockDim.x + threadIdx.x;
    if (e < N_EDGES) {
        atomicAdd(&histD[dst[e]], 1);
        atomicAdd(&histP[rel[e] * SB + src[e]], 1);
    }
}

// ---- dst-offset scan (49 blocks) ----
__global__ void k_scanA(const int* __restrict__ hist, int* __restrict__ partials) {
    __shared__ int red[256];
    int b = blockIdx.x, t = threadIdx.x;
    int4 v = ((const int4*)(hist + b * 1024))[t];
    red[t] = v.x + v.y + v.z + v.w;
    __syncthreads();
    for (int o = 128; o > 0; o >>= 1) {
        if (t < o) red[t] += red[t + o];
        __syncthreads();
    }
    if (t == 0) partials[b] = red[0];
}

__global__ void k_scanB(int* __restrict__ partials, int* __restrict__ offs_tail) {
    __shared__ int s1[256], s2[256];
    int t = threadIdx.x;
    int v = (t < NBLK_PD) ? partials[t] : 0;
    s1[t] = v; __syncthreads();
    int* cur = s1; int* nxt = s2;
    for (int o = 1; o < 256; o <<= 1) {
        nxt[t] = cur[t] + ((t >= o) ? cur[t - o] : 0);
        __syncthreads();
        int* tmp = cur; cur = nxt; nxt = tmp;
    }
    if (t < NBLK_PD) partials[t] = cur[t] - v;           // exclusive
    if (t == 255) offs_tail[0] = cur[255];
}

__global__ void k_scanC(const int* __restrict__ hist, const int* __restrict__ partials,
                        int* __restrict__ offs, int* __restrict__ curp) {
    __shared__ int s1[256], s2[256];
    int b = blockIdx.x, t = threadIdx.x;
    int4 v = ((const int4*)(hist + b * 1024))[t];
    int sum = v.x + v.y + v.z + v.w;
    s1[t] = sum; __syncthreads();
    int* cur = s1; int* nxt = s2;
    for (int o = 1; o < 256; o <<= 1) {
        nxt[t] = cur[t] + ((t >= o) ? cur[t - o] : 0);
        __syncthreads();
        int* tmp = cur; cur = nxt; nxt = tmp;
    }
    int base = partials[b] + cur[t] - sum;
    int4 w;
    w.x = base;
    w.y = base + v.x;
    w.z = w.y + v.y;
    w.w = w.z + v.z;
    ((int4*)(offs + b * 1024))[t] = w;
    ((int4*)(curp + b * 1024))[t] = w;
}

// ---- pair (rel,src) dedup scan ----
__global__ void k_scanPA(const int* __restrict__ histP, int* __restrict__ partP) {
    __shared__ int red[256];
    int b = blockIdx.x, t = threadIdx.x;
    int4 v = ((const int4*)(histP + b * 1024))[t];
    red[t] = (v.x > 0) + (v.y > 0) + (v.z > 0) + (v.w > 0);
    __syncthreads();
    for (int o = 128; o > 0; o >>= 1) {
        if (t < o) red[t] += red[t + o];
        __syncthreads();
    }
    if (t == 0) partP[b] = red[0];
}

// serial (784 elems): per-rel 64-padded bases + per-block bases
__global__ void k_scanPB(const int* __restrict__ partP, int* __restrict__ blkB,
                         int* __restrict__ relB) {
    if (threadIdx.x == 0 && blockIdx.x == 0) {
        int base = 0;
        for (int r = 0; r < 16; ++r) {
            relB[r] = base;
            int ru = 0;
            for (int b = r * 49; b < (r + 1) * 49; ++b) {
                blkB[b] = base + ru;
                ru += partP[b];
            }
            base += (ru + 63) & ~63;
        }
        relB[16] = base;                                 // RTOT = self base
    }
}

__global__ void k_scanPC(const int* __restrict__ histP, const int* __restrict__ blkB,
                         int* __restrict__ cidMap, int* __restrict__ srcOf) {
    __shared__ int s1[256], s2[256];
    int b = blockIdx.x, t = threadIdx.x;
    int4 v = ((const int4*)(histP + b * 1024))[t];
    int f0 = v.x > 0, f1 = v.y > 0, f2 = v.z > 0, f3 = v.w > 0;
    int sum = f0 + f1 + f2 + f3;
    s1[t] = sum; __syncthreads();
    int* cur = s1; int* nxt = s2;
    for (int o = 1; o < 256; o <<= 1) {
        nxt[t] = cur[t] + ((t >= o) ? cur[t - o] : 0);
        __syncthreads();
        int* tmp = cur; cur = nxt; nxt = tmp;
    }
    int cid = blkB[b] + cur[t] - sum;
    int rel = b / 49;
    int key0 = b * 1024 + t * 4;
    int srcBase = key0 - rel * SB;
    if (f0) { cidMap[key0]     = cid; srcOf[cid] = srcBase;     cid++; }
    if (f1) { cidMap[key0 + 1] = cid; srcOf[cid] = srcBase + 1; cid++; }
    if (f2) { cidMap[key0 + 2] = cid; srcOf[cid] = srcBase + 2; cid++; }
    if (f3) { cidMap[key0 + 3] = cid; srcOf[cid] = srcBase + 3; cid++; }
}

__global__ void k_scatterK(const int* __restrict__ src, const int* __restrict__ dst,
                           const int* __restrict__ rel, const int* __restrict__ cidMap,
                           int* __restrict__ curD, unsigned int* __restrict__ recs) {
    int e = blockIdx.x * blockDim.x + threadIdx.x;
    if (e < N_EDGES) {
        int cid = cidMap[rel[e] * SB + src[e]];
        int pos = atomicAdd(&curD[dst[e]], 1);
        recs[pos] = (unsigned int)cid;
    }
}

// ---- Phase A: gather-GEMM over compact rows (one rel per block by padding) ----
__global__ __launch_bounds__(256) void k_phaseA(
    const unsigned short* __restrict__ x, const unsigned short* __restrict__ Wb,
    const int* __restrict__ srcOf, const int* __restrict__ relB,
    unsigned short* __restrict__ T)
{
    __shared__ unsigned short Xs[64 * 136];
    __shared__ unsigned short Cs[64 * 136];
    __shared__ int sSrc[64];
    __shared__ int sRB[17];

    int tid = threadIdx.x;
    if (tid < 17) sRB[tid] = relB[tid];
    __syncthreads();

    int row0 = blockIdx.x * 64;
    int rtot = sRB[16];
    if (row0 >= rtot + N_PAD) return;                    // uniform exit

    int r = 16;
    #pragma unroll
    for (int i = 0; i < 16; ++i)
        if (row0 < sRB[i + 1]) { r = i; break; }

    if (tid < 64) sSrc[tid] = (r == 16) ? (row0 - rtot + tid) : srcOf[row0 + tid];
    __syncthreads();

    {   // gather-stage X rows: 4 threads/row
        int row = tid >> 2, c0 = tid & 3;
        const uint4* xp = (const uint4*)(x + (size_t)sSrc[row] * DIM);
        uint4* lp = (uint4*)(&Xs[row * 136]);
        #pragma unroll
        for (int i = 0; i < 4; ++i) lp[c0 + 4 * i] = xp[c0 + 4 * i];
    }
    __syncthreads();

    int w = tid >> 6, l = tid & 63;
    int nl = l & 15, q = l >> 4;

    bf16x8 Bf[2][4];
    const unsigned short* wr = Wb + r * 16384;
    #pragma unroll
    for (int nt = 0; nt < 2; ++nt) {
        int n = w * 32 + nt * 16 + nl;
        #pragma unroll
        for (int kc = 0; kc < 4; ++kc)
            Bf[nt][kc] = *(const bf16x8*)(wr + n * 128 + kc * 32 + q * 8);
    }
    #pragma unroll
    for (int m = 0; m < 4; ++m) {
        f32x4 a0 = {0.f,0.f,0.f,0.f}, a1 = {0.f,0.f,0.f,0.f};
        #pragma unroll
        for (int kc = 0; kc < 4; ++kc) {
            bf16x8 a = *(const bf16x8*)(&Xs[(m * 16 + nl) * 136 + kc * 32 + q * 8]);
            a0 = __builtin_amdgcn_mfma_f32_16x16x32_bf16(a, Bf[0][kc], a0, 0, 0, 0);
            a1 = __builtin_amdgcn_mfma_f32_16x16x32_bf16(a, Bf[1][kc], a1, 0, 0, 0);
        }
        int col = w * 32 + nl;                           // C: col=lane&15, row=q*4+reg
        #pragma unroll
        for (int reg = 0; reg < 4; ++reg) {
            int row = m * 16 + q * 4 + reg;
            Cs[row * 136 + col]      = f2bf(a0[reg]);
            Cs[row * 136 + col + 16] = f2bf(a1[reg]);
        }
    }
    __syncthreads();
    {   // coalesced store: 1024 uint4 chunks, 4/thread
        unsigned short* Tb = T + (size_t)row0 * DIM;
        #pragma unroll
        for (int it = 0; it < 4; ++it) {
            int c = tid + it * 256;
            int row = c >> 4, k8 = c & 15;
            uint4 vv = *(const uint4*)(&Cs[row * 136 + k8 * 8]);
            *(uint4*)(Tb + row * DIM + k8 * 8) = vv;
        }
    }
}

// ---- Phase B: 32 dsts/block, 8 lanes/dst; compact-id rows, single pass ----
__global__ __launch_bounds__(256) void k_phaseB(
    const unsigned short* __restrict__ T, const unsigned int* __restrict__ recs,
    const int* __restrict__ offsD, const int* __restrict__ relB,
    const float* __restrict__ bias,
    unsigned short* __restrict__ aggOut, int relu)
{
    __shared__ int sOffs[33];
    __shared__ float sBias[128];
    __shared__ int sSelf;
    int tid = threadIdx.x;
    int v0 = blockIdx.x * 32;
    if (tid < 33) sOffs[tid] = offsD[v0 + tid];
    if (tid == 40) sSelf = relB[16];
    if (tid >= 64 && tid < 96) ((float4*)sBias)[tid - 64] = ((const float4*)bias)[tid - 64];
    __syncthreads();

    int g = tid >> 3, s = tid & 7;
    int dst = v0 + g;
    float qa[16];
    #pragma unroll
    for (int i = 0; i < 16; ++i) qa[i] = sBias[s * 16 + i];

    int beg = sOffs[g], end = sOffs[g + 1];
    int e = beg;
    for (; e + 3 < end; e += 4) {
        unsigned int c0 = recs[e], c1 = recs[e+1], c2 = recs[e+2], c3 = recs[e+3];
        const uint4* t0 = (const uint4*)(T + (size_t)c0 * DIM + s * 16);
        const uint4* t1 = (const uint4*)(T + (size_t)c1 * DIM + s * 16);
        const uint4* t2 = (const uint4*)(T + (size_t)c2 * DIM + s * 16);
        const uint4* t3 = (const uint4*)(T + (size_t)c3 * DIM + s * 16);
        uint4 a0 = t0[0], a1 = t0[1], b0 = t1[0], b1 = t1[1];
        uint4 cc0 = t2[0], cc1 = t2[1], d0 = t3[0], d1 = t3[1];
        accum8(qa, a0); accum8(qa + 8, a1);
        accum8(qa, b0); accum8(qa + 8, b1);
        accum8(qa, cc0); accum8(qa + 8, cc1);
        accum8(qa, d0); accum8(qa + 8, d1);
    }
    for (; e < end; ++e) {
        unsigned int c = recs[e];
        const uint4* tp = (const uint4*)(T + (size_t)c * DIM + s * 16);
        uint4 u0 = tp[0], u1 = tp[1];
        accum8(qa, u0); accum8(qa + 8, u1);
    }
    {   // self-loop row
        const uint4* tp = (const uint4*)(T + (size_t)(sSelf + dst) * DIM + s * 16);
        uint4 u0 = tp[0], u1 = tp[1];
        accum8(qa, u0); accum8(qa + 8, u1);
    }

    if (relu) {
        #pragma unroll
        for (int i = 0; i < 16; ++i) qa[i] = fmaxf(qa[i], 0.f);
    }
    pack16(qa, aggOut + (size_t)dst * DIM + s * 16);
}

__global__ void k_pool(const unsigned short* __restrict__ agg2, const int* __restrict__ gids,
                       float* __restrict__ hg_sum, int* __restrict__ cnt)
{
    int d  = threadIdx.x;
    int n0 = blockIdx.x * POOL_CH;
    int nend = min(n0 + POOL_CH, N_NODES);
    int curg = gids[n0];
    float run = 0.f;
    for (int n = n0; n < nend; ++n) {
        int g = gids[n];
        if (g != curg) { atomAddF(&hg_sum[curg*DIM + d], run); run = 0.f; curg = g; }
        run += fmaxf(bf2f((unsigned int)agg2[n*DIM + d]), 0.f);
    }
    atomAddF(&hg_sum[curg*DIM + d], run);
    if (d == 0) {
        int cg = gids[n0]; int rl = 0;
        for (int n = n0; n < nend; ++n) {
            int g = gids[n];
            if (g != cg) { atomicAdd(&cnt[cg], rl); rl = 0; cg = g; }
            rl++;
        }
        atomicAdd(&cnt[cg], rl);
    }
}

__global__ __launch_bounds__(256) void k_head(
    const float* __restrict__ hg_sum, const int* __restrict__ cnt,
    const float* __restrict__ Wfc, const float* __restrict__ bfc,
    const float* __restrict__ Wc, const float* __restrict__ bc,
    float* __restrict__ out)
{
    int g = blockIdx.x, t = threadIdx.x;
    __shared__ float hgl[DIM];
    __shared__ float fcl[FC_DIM];
    __shared__ float lg[N_CLASSES];
    if (t < DIM) {
        float c = (float)max(cnt[g], 1);
        hgl[t] = hg_sum[g*DIM + t] / c;
    }
    __syncthreads();
    {
        float sv = bfc[t];
        #pragma unroll 4
        for (int k = 0; k < DIM; ++k) sv += hgl[k] * Wfc[k*FC_DIM + t];
        fcl[t] = fmaxf(sv, 0.f);
    }
    __syncthreads();
    if (t < N_CLASSES) {
        float lgt = bc[t];
        #pragma unroll 4
        for (int k = 0; k < FC_DIM; ++k) lgt += fcl[k] * Wc[k*N_CLASSES + t];
        lg[t] = lgt;
    }
    __syncthreads();
    if (t < N_CLASSES) {
        float m = lg[0];
        #pragma unroll
        for (int c = 1; c < N_CLASSES; ++c) m = fmaxf(m, lg[c]);
        float sden = 0.f;
        #pragma unroll
        for (int c = 0; c < N_CLASSES; ++c) sden += expf(lg[c] - m);
        out[g*N_CLASSES + t] = expf(lg[t] - m) / sden;
    }
}

extern "C" void kernel_launch(void* const* d_in, const int* in_sizes, int n_in,
                              void* d_out, int out_size, void* d_ws, size_t ws_size,
                              hipStream_t stream)
{
    const float* h   = (const float*)d_in[0];
    const int*   src = (const int*)d_in[1];
    const int*   dst = (const int*)d_in[2];
    const int*   rel = (const int*)d_in[3];
    const int*   gid = (const int*)d_in[4];
    const float* W1  = (const float*)d_in[5];
    const float* Ws1 = (const float*)d_in[6];
    const float* b1  = (const float*)d_in[7];
    const float* W2  = (const float*)d_in[8];
    const float* Ws2 = (const float*)d_in[9];
    const float* b2  = (const float*)d_in[10];
    const float* Wfc = (const float*)d_in[11];
    const float* bfc = (const float*)d_in[12];
    const float* Wc  = (const float*)d_in[13];
    const float* bc  = (const float*)d_in[14];
    float* out = (float*)d_out;

    char* ws = (char*)d_ws;
    int*   histP = (int*)(ws + WS_HISTP);
    int*   histD = (int*)(ws + WS_HISTD);
    float* hgsum = (float*)(ws + WS_HG);
    int*   cnt   = (int*)(ws + WS_CNT);
    int*   srcOf = (int*)(ws + WS_SRCOF);
    int*   offsD = (int*)(ws + WS_OFFSD);
    int*   curD  = (int*)(ws + WS_CURD);
    int*   partD = (int*)(ws + WS_PARTD);
    int*   partP = (int*)(ws + WS_PARTP);
    int*   blkB  = (int*)(ws + WS_BLKB);
    int*   relB  = (int*)(ws + WS_RELB);
    int*   cidMap= (int*)(ws + WS_CIDMAP);
    unsigned int* recs = (unsigned int*)(ws + WS_RECS);
    unsigned short* x1  = (unsigned short*)(ws + WS_X1);
    unsigned short* x2  = (unsigned short*)(ws + WS_X2);
    unsigned short* agg = (unsigned short*)(ws + WS_AGG);
    unsigned short* Wb  = (unsigned short*)(ws + WS_WB);
    unsigned short* T   = (unsigned short*)(ws + WS_T);

    // cap phaseA grid by T capacity (host constant -> capture-safe)
    int gridA = MAXBLK_A;
    if (ws_size > (size_t)WS_T) {
        long long capRows = (long long)((ws_size - WS_T) / 256);
        long long capBlk = capRows / 64;
        if (capBlk < gridA) gridA = (int)capBlk;
    }

    hipMemsetAsync(histP, 0, MEMSET_SZ, stream);   // histP+histD+hg+cnt+srcOf

    k_convXW<<<XW_TOTAL / 256, 256, 0, stream>>>(h, x1, W1, Ws1, W2, Ws2, Wb);
    k_hist2<<<(N_EDGES + 255) / 256, 256, 0, stream>>>(src, dst, rel, histP, histD);

    k_scanA<<<NBLK_PD, 256, 0, stream>>>(histD, partD);
    k_scanB<<<1, 256, 0, stream>>>(partD, offsD + NBINS_D);
    k_scanC<<<NBLK_PD, 256, 0, stream>>>(histD, partD, offsD, curD);

    k_scanPA<<<NBLK_PP, 256, 0, stream>>>(histP, partP);
    k_scanPB<<<1, 64, 0, stream>>>(partP, blkB, relB);
    k_scanPC<<<NBLK_PP, 256, 0, stream>>>(histP, blkB, cidMap, srcOf);

    k_scatterK<<<(N_EDGES + 255) / 256, 256, 0, stream>>>(src, dst, rel, cidMap, curD, recs);

    k_phaseA<<<gridA, 256, 0, stream>>>(x1, Wb, srcOf, relB, T);
    k_phaseB<<<N_PAD / 32, 256, 0, stream>>>(T, recs, offsD, relB, b1, x2, 1);
    k_phaseA<<<gridA, 256, 0, stream>>>(x2, Wb + 17 * 16384, srcOf, relB, T);
    k_phaseB<<<N_PAD / 32, 256, 0, stream>>>(T, recs, offsD, relB, b2, agg, 0);

    k_pool<<<(N_PAD + POOL_CH - 1) / POOL_CH, 128, 0, stream>>>(agg, gid, hgsum, cnt);
    k_head<<<N_GRAPHS, 256, 0, stream>>>(hgsum, cnt, Wfc, bfc, Wc, bc, out);
}

// Round 13
// 454.960 us; speedup vs baseline: 3.8762x; 1.0937x over previous
//
#include <hip/hip_runtime.h>
#include <hip/hip_bf16.h>

#define N_NODES   50000
#define N_PAD     50048                 // ceil64
#define N_EDGES   800000
#define N_REL     16
#define N_GRAPHS  64
#define DIM       128
#define FC_DIM    256
#define N_CLASSES 16

#define SB        50176                 // src bins per rel (49*1024)
#define NBINS_P   (16 * SB)             // 802816, key = rel*SB + src
#define NBLK_PP   784
#define NBINS_D   50176                 // dst bins (49*1024)
#define NBLK_PD   49
#define POOL_CH   64
#define MAXBLK_A  13294                 // (16*50048 + 50048)/64 worst case

// ---- ws layout (bytes, 256-aligned) ----
#define WS_MARK   0                     // 802816 bytes } contiguous
#define WS_HISTD  802816                // 200704       } memset
#define WS_HG     1003520               // 32768        } region
#define WS_CNT    1036288               // 256          }
#define WS_SRCOF  1036544               // 3203072      } (pads must be 0)
#define MEMSET_SZ 4239616
#define WS_OFFSD  4239616               // 200960
#define WS_CURD   4440576               // 200704
#define WS_PARTD  4641280               // 256
#define WS_PARTP  4641536               // 3328
#define WS_BLKB   4644864               // 3328
#define WS_RELB   4648192               // 256 (relBase[0..16], [16]=RTOT)
#define WS_CIDMAP 4648448               // 3211264
#define WS_RECS   7859712               // 3200000
#define WS_X1     11059712              // 12812288
#define WS_X2     23872000              // 12812288
#define WS_AGG    36684288              // 12812288 (bf16)
#define WS_WB     49496576              // 1114112
#define WS_T      50610688              // + rows*256B (actual ~142MB)

#define XW_TOTAL  (N_PAD * DIM + 2 * 17 * 16384)   // 6963200

typedef __attribute__((ext_vector_type(8))) short bf16x8;
typedef __attribute__((ext_vector_type(4))) float f32x4;

__device__ __forceinline__ void atomAddF(float* p, float v) {
#if defined(__gfx90a__) || defined(__gfx942__) || defined(__gfx950__)
    unsafeAtomicAdd(p, v);
#else
    atomicAdd(p, v);
#endif
}

__device__ __forceinline__ float bf2f(unsigned int u) {
    union { float f; unsigned int i; } x; x.i = u << 16; return x.f;
}
__device__ __forceinline__ unsigned short f2bf(float f) {
    union { float f; unsigned int u; } x; x.f = f;
    unsigned int r = x.u + 0x7fff + ((x.u >> 16) & 1);
    return (unsigned short)(r >> 16);
}
__device__ __forceinline__ void accum8(float* qa, uint4 u) {
    qa[0] += bf2f(u.x & 0xffff); qa[1] += bf2f(u.x >> 16);
    qa[2] += bf2f(u.y & 0xffff); qa[3] += bf2f(u.y >> 16);
    qa[4] += bf2f(u.z & 0xffff); qa[5] += bf2f(u.z >> 16);
    qa[6] += bf2f(u.w & 0xffff); qa[7] += bf2f(u.w >> 16);
}
__device__ __forceinline__ void pack16(const float* qa, unsigned short* dst) {
    #pragma unroll
    for (int j = 0; j < 2; ++j) {
        uint4 w;
        w.x = ((unsigned int)f2bf(qa[j*8+1]) << 16) | f2bf(qa[j*8+0]);
        w.y = ((unsigned int)f2bf(qa[j*8+3]) << 16) | f2bf(qa[j*8+2]);
        w.z = ((unsigned int)f2bf(qa[j*8+5]) << 16) | f2bf(qa[j*8+4]);
        w.w = ((unsigned int)f2bf(qa[j*8+7]) << 16) | f2bf(qa[j*8+6]);
        ((uint4*)dst)[j] = w;
    }
}

// merged convX + convW
__global__ void k_convXW(const float* __restrict__ h, unsigned short* __restrict__ x1,
                         const float* __restrict__ W1, const float* __restrict__ Ws1,
                         const float* __restrict__ W2, const float* __restrict__ Ws2,
                         unsigned short* __restrict__ Wb) {
    int id = blockIdx.x * blockDim.x + threadIdx.x;
    if (id < N_PAD * DIM) {
        int v = id >> 7;
        x1[id] = (v < N_NODES) ? f2bf(h[id]) : (unsigned short)0;
    } else {
        int t = id - N_PAD * DIM;
        int l = t / 278528, rem = t % 278528;
        int r = rem >> 14, rr = rem & 16383;
        int n = rr >> 7, k = rr & 127;
        const float* W  = l ? W2 : W1;
        const float* Ws = l ? Ws2 : Ws1;
        float v = (r < 16) ? W[r * 16384 + k * 128 + n] : Ws[k * 128 + n];
        Wb[t] = f2bf(v);
    }
}

// dst histogram (atomic) + pair existence mark (plain store, benign race)
__global__ void k_hist2(const int* __restrict__ src, const int* __restrict__ dst,
                        const int* __restrict__ rel,
                        unsigned char* __restrict__ mark, int* __restrict__ histD) {
    int e = blockIdx.x * blockDim.x + threadIdx.x;
    if (e < N_EDGES) {
        atomicAdd(&histD[dst[e]], 1);
        mark[rel[e] * SB + src[e]] = 1;
    }
}

// ---- dst-offset scan (49 blocks) ----
__global__ void k_scanA(const int* __restrict__ hist, int* __restrict__ partials) {
    __shared__ int red[256];
    int b = blockIdx.x, t = threadIdx.x;
    int4 v = ((const int4*)(hist + b * 1024))[t];
    red[t] = v.x + v.y + v.z + v.w;
    __syncthreads();
    for (int o = 128; o > 0; o >>= 1) {
        if (t < o) red[t] += red[t + o];
        __syncthreads();
    }
    if (t == 0) partials[b] = red[0];
}

__global__ void k_scanB(int* __restrict__ partials, int* __restrict__ offs_tail) {
    __shared__ int s1[256], s2[256];
    int t = threadIdx.x;
    int v = (t < NBLK_PD) ? partials[t] : 0;
    s1[t] = v; __syncthreads();
    int* cur = s1; int* nxt = s2;
    for (int o = 1; o < 256; o <<= 1) {
        nxt[t] = cur[t] + ((t >= o) ? cur[t - o] : 0);
        __syncthreads();
        int* tmp = cur; cur = nxt; nxt = tmp;
    }
    if (t < NBLK_PD) partials[t] = cur[t] - v;           // exclusive
    if (t == 255) offs_tail[0] = cur[255];
}

__global__ void k_scanC(const int* __restrict__ hist, const int* __restrict__ partials,
                        int* __restrict__ offs, int* __restrict__ curp) {
    __shared__ int s1[256], s2[256];
    int b = blockIdx.x, t = threadIdx.x;
    int4 v = ((const int4*)(hist + b * 1024))[t];
    int sum = v.x + v.y + v.z + v.w;
    s1[t] = sum; __syncthreads();
    int* cur = s1; int* nxt = s2;
    for (int o = 1; o < 256; o <<= 1) {
        nxt[t] = cur[t] + ((t >= o) ? cur[t - o] : 0);
        __syncthreads();
        int* tmp = cur; cur = nxt; nxt = tmp;
    }
    int base = partials[b] + cur[t] - sum;
    int4 w;
    w.x = base;
    w.y = base + v.x;
    w.z = w.y + v.y;
    w.w = w.z + v.z;
    ((int4*)(offs + b * 1024))[t] = w;
    ((int4*)(curp + b * 1024))[t] = w;
}

// ---- pair dedup: count marked per 1024-bin block ----
__global__ void k_scanPA(const unsigned int* __restrict__ markU, int* __restrict__ partP) {
    __shared__ int red[256];
    int b = blockIdx.x, t = threadIdx.x;
    unsigned int u = markU[b * 256 + t];
    red[t] = (int)((u & 1) + ((u >> 8) & 1) + ((u >> 16) & 1) + ((u >> 24) & 1));
    __syncthreads();
    for (int o = 128; o > 0; o >>= 1) {
        if (t < o) red[t] += red[t + o];
        __syncthreads();
    }
    if (t == 0) partP[b] = red[0];
}

// parallel segmented scan over 784 block-counts: 16 rel-segments x 49,
// per-rel totals rounded up to 64 for the base offsets
__global__ void k_scanPB(const int* __restrict__ partP, int* __restrict__ blkB,
                         int* __restrict__ relB) {
    __shared__ int s1[784], s2[784];
    __shared__ int tot[16], rbase[17];
    int t = threadIdx.x;                                 // blockDim = 1024
    int rel = t / 49, pos = t - rel * 49;
    int v = (t < 784) ? partP[t] : 0;
    if (t < 784) s1[t] = v;
    __syncthreads();
    int* cur = s1; int* nxt = s2;
    for (int o = 1; o < 64; o <<= 1) {
        if (t < 784) nxt[t] = cur[t] + ((pos >= o) ? cur[t - o] : 0);
        __syncthreads();
        int* tmp = cur; cur = nxt; nxt = tmp;
    }
    if (t < 784 && pos == 48) tot[rel] = cur[t];
    __syncthreads();
    if (t == 0) {
        int base = 0;
        for (int r = 0; r < 16; ++r) { rbase[r] = base; base += (tot[r] + 63) & ~63; }
        rbase[16] = base;
    }
    __syncthreads();
    if (t < 784) blkB[t] = rbase[rel] + cur[t] - v;      // exclusive within segment
    if (t < 17)  relB[t] = rbase[t];
}

__global__ void k_scanPC(const unsigned int* __restrict__ markU, const int* __restrict__ blkB,
                         int* __restrict__ cidMap, int* __restrict__ srcOf) {
    __shared__ int s1[256], s2[256];
    int b = blockIdx.x, t = threadIdx.x;
    unsigned int u = markU[b * 256 + t];
    int f0 = (int)(u & 1), f1 = (int)((u >> 8) & 1);
    int f2 = (int)((u >> 16) & 1), f3 = (int)((u >> 24) & 1);
    int sum = f0 + f1 + f2 + f3;
    s1[t] = sum; __syncthreads();
    int* cur = s1; int* nxt = s2;
    for (int o = 1; o < 256; o <<= 1) {
        nxt[t] = cur[t] + ((t >= o) ? cur[t - o] : 0);
        __syncthreads();
        int* tmp = cur; cur = nxt; nxt = tmp;
    }
    int cid = blkB[b] + cur[t] - sum;
    int rel = b / 49;
    int key0 = b * 1024 + t * 4;
    int srcBase = key0 - rel * SB;
    if (f0) { cidMap[key0]     = cid; srcOf[cid] = srcBase;     cid++; }
    if (f1) { cidMap[key0 + 1] = cid; srcOf[cid] = srcBase + 1; cid++; }
    if (f2) { cidMap[key0 + 2] = cid; srcOf[cid] = srcBase + 2; cid++; }
    if (f3) { cidMap[key0 + 3] = cid; srcOf[cid] = srcBase + 3; cid++; }
}

__global__ void k_scatterK(const int* __restrict__ src, const int* __restrict__ dst,
                           const int* __restrict__ rel, const int* __restrict__ cidMap,
                           int* __restrict__ curD, unsigned int* __restrict__ recs) {
    int e = blockIdx.x * blockDim.x + threadIdx.x;
    if (e < N_EDGES) {
        int cid = cidMap[rel[e] * SB + src[e]];
        int pos = atomicAdd(&curD[dst[e]], 1);
        recs[pos] = (unsigned int)cid;
    }
}

// ---- Phase A: gather-GEMM over compact rows (one rel per block by padding) ----
__global__ __launch_bounds__(256) void k_phaseA(
    const unsigned short* __restrict__ x, const unsigned short* __restrict__ Wb,
    const int* __restrict__ srcOf, const int* __restrict__ relB,
    unsigned short* __restrict__ T)
{
    __shared__ unsigned short Xs[64 * 136];
    __shared__ unsigned short Cs[64 * 136];
    __shared__ int sSrc[64];
    __shared__ int sRB[17];

    int tid = threadIdx.x;
    if (tid < 17) sRB[tid] = relB[tid];
    __syncthreads();

    int row0 = blockIdx.x * 64;
    int rtot = sRB[16];
    if (row0 >= rtot + N_PAD) return;                    // uniform exit

    int r = 16;
    #pragma unroll
    for (int i = 0; i < 16; ++i)
        if (row0 < sRB[i + 1]) { r = i; break; }

    if (tid < 64) sSrc[tid] = (r == 16) ? (row0 - rtot + tid) : srcOf[row0 + tid];
    __syncthreads();

    {   // gather-stage X rows: 4 threads/row
        int row = tid >> 2, c0 = tid & 3;
        const uint4* xp = (const uint4*)(x + (size_t)sSrc[row] * DIM);
        uint4* lp = (uint4*)(&Xs[row * 136]);
        #pragma unroll
        for (int i = 0; i < 4; ++i) lp[c0 + 4 * i] = xp[c0 + 4 * i];
    }
    __syncthreads();

    int w = tid >> 6, l = tid & 63;
    int nl = l & 15, q = l >> 4;

    bf16x8 Bf[2][4];
    const unsigned short* wr = Wb + r * 16384;
    #pragma unroll
    for (int nt = 0; nt < 2; ++nt) {
        int n = w * 32 + nt * 16 + nl;
        #pragma unroll
        for (int kc = 0; kc < 4; ++kc)
            Bf[nt][kc] = *(const bf16x8*)(wr + n * 128 + kc * 32 + q * 8);
    }
    #pragma unroll
    for (int m = 0; m < 4; ++m) {
        f32x4 a0 = {0.f,0.f,0.f,0.f}, a1 = {0.f,0.f,0.f,0.f};
        #pragma unroll
        for (int kc = 0; kc < 4; ++kc) {
            bf16x8 a = *(const bf16x8*)(&Xs[(m * 16 + nl) * 136 + kc * 32 + q * 8]);
            a0 = __builtin_amdgcn_mfma_f32_16x16x32_bf16(a, Bf[0][kc], a0, 0, 0, 0);
            a1 = __builtin_amdgcn_mfma_f32_16x16x32_bf16(a, Bf[1][kc], a1, 0, 0, 0);
        }
        int col = w * 32 + nl;                           // C: col=lane&15, row=q*4+reg
        #pragma unroll
        for (int reg = 0; reg < 4; ++reg) {
            int row = m * 16 + q * 4 + reg;
            Cs[row * 136 + col]      = f2bf(a0[reg]);
            Cs[row * 136 + col + 16] = f2bf(a1[reg]);
        }
    }
    __syncthreads();
    {   // coalesced store: 1024 uint4 chunks, 4/thread
        unsigned short* Tb = T + (size_t)row0 * DIM;
        #pragma unroll
        for (int it = 0; it < 4; ++it) {
            int c = tid + it * 256;
            int row = c >> 4, k8 = c & 15;
            uint4 vv = *(const uint4*)(&Cs[row * 136 + k8 * 8]);
            *(uint4*)(Tb + row * DIM + k8 * 8) = vv;
        }
    }
}

// ---- Phase B: 32 dsts/block, 8 lanes/dst; compact-id rows, single pass ----
__global__ __launch_bounds__(256) void k_phaseB(
    const unsigned short* __restrict__ T, const unsigned int* __restrict__ recs,
    const int* __restrict__ offsD, const int* __restrict__ relB,
    const float* __restrict__ bias,
    unsigned short* __restrict__ aggOut, int relu)
{
    __shared__ int sOffs[33];
    __shared__ float sBias[128];
    __shared__ int sSelf;
    int tid = threadIdx.x;
    int v0 = blockIdx.x * 32;
    if (tid < 33) sOffs[tid] = offsD[v0 + tid];
    if (tid == 40) sSelf = relB[16];
    if (tid >= 64 && tid < 96) ((float4*)sBias)[tid - 64] = ((const float4*)bias)[tid - 64];
    __syncthreads();

    int g = tid >> 3, s = tid & 7;
    int dst = v0 + g;
    float qa[16];
    #pragma unroll
    for (int i = 0; i < 16; ++i) qa[i] = sBias[s * 16 + i];

    int beg = sOffs[g], end = sOffs[g + 1];
    int e = beg;
    for (; e + 3 < end; e += 4) {
        unsigned int c0 = recs[e], c1 = recs[e+1], c2 = recs[e+2], c3 = recs[e+3];
        const uint4* t0 = (const uint4*)(T + (size_t)c0 * DIM + s * 16);
        const uint4* t1 = (const uint4*)(T + (size_t)c1 * DIM + s * 16);
        const uint4* t2 = (const uint4*)(T + (size_t)c2 * DIM + s * 16);
        const uint4* t3 = (const uint4*)(T + (size_t)c3 * DIM + s * 16);
        uint4 a0 = t0[0], a1 = t0[1], b0 = t1[0], b1 = t1[1];
        uint4 cc0 = t2[0], cc1 = t2[1], d0 = t3[0], d1 = t3[1];
        accum8(qa, a0); accum8(qa + 8, a1);
        accum8(qa, b0); accum8(qa + 8, b1);
        accum8(qa, cc0); accum8(qa + 8, cc1);
        accum8(qa, d0); accum8(qa + 8, d1);
    }
    for (; e < end; ++e) {
        unsigned int c = recs[e];
        const uint4* tp = (const uint4*)(T + (size_t)c * DIM + s * 16);
        uint4 u0 = tp[0], u1 = tp[1];
        accum8(qa, u0); accum8(qa + 8, u1);
    }
    {   // self-loop row
        const uint4* tp = (const uint4*)(T + (size_t)(sSelf + dst) * DIM + s * 16);
        uint4 u0 = tp[0], u1 = tp[1];
        accum8(qa, u0); accum8(qa + 8, u1);
    }

    if (relu) {
        #pragma unroll
        for (int i = 0; i < 16; ++i) qa[i] = fmaxf(qa[i], 0.f);
    }
    pack16(qa, aggOut + (size_t)dst * DIM + s * 16);
}

__global__ void k_pool(const unsigned short* __restrict__ agg2, const int* __restrict__ gids,
                       float* __restrict__ hg_sum, int* __restrict__ cnt)
{
    int d  = threadIdx.x;
    int n0 = blockIdx.x * POOL_CH;
    int nend = min(n0 + POOL_CH, N_NODES);
    if (n0 >= N_NODES) return;
    int curg = gids[n0];
    float run = 0.f;
    for (int n = n0; n < nend; ++n) {
        int g = gids[n];
        if (g != curg) { atomAddF(&hg_sum[curg*DIM + d], run); run = 0.f; curg = g; }
        run += fmaxf(bf2f((unsigned int)agg2[n*DIM + d]), 0.f);
    }
    atomAddF(&hg_sum[curg*DIM + d], run);
    if (d == 0) {
        int cg = gids[n0]; int rl = 0;
        for (int n = n0; n < nend; ++n) {
            int g = gids[n];
            if (g != cg) { atomicAdd(&cnt[cg], rl); rl = 0; cg = g; }
            rl++;
        }
        atomicAdd(&cnt[cg], rl);
    }
}

__global__ __launch_bounds__(256) void k_head(
    const float* __restrict__ hg_sum, const int* __restrict__ cnt,
    const float* __restrict__ Wfc, const float* __restrict__ bfc,
    const float* __restrict__ Wc, const float* __restrict__ bc,
    float* __restrict__ out)
{
    int g = blockIdx.x, t = threadIdx.x;
    __shared__ float hgl[DIM];
    __shared__ float fcl[FC_DIM];
    __shared__ float lg[N_CLASSES];
    if (t < DIM) {
        float c = (float)max(cnt[g], 1);
        hgl[t] = hg_sum[g*DIM + t] / c;
    }
    __syncthreads();
    {
        float sv = bfc[t];
        #pragma unroll 4
        for (int k = 0; k < DIM; ++k) sv += hgl[k] * Wfc[k*FC_DIM + t];
        fcl[t] = fmaxf(sv, 0.f);
    }
    __syncthreads();
    if (t < N_CLASSES) {
        float lgt = bc[t];
        #pragma unroll 4
        for (int k = 0; k < FC_DIM; ++k) lgt += fcl[k] * Wc[k*N_CLASSES + t];
        lg[t] = lgt;
    }
    __syncthreads();
    if (t < N_CLASSES) {
        float m = lg[0];
        #pragma unroll
        for (int c = 1; c < N_CLASSES; ++c) m = fmaxf(m, lg[c]);
        float sden = 0.f;
        #pragma unroll
        for (int c = 0; c < N_CLASSES; ++c) sden += expf(lg[c] - m);
        out[g*N_CLASSES + t] = expf(lg[t] - m) / sden;
    }
}

extern "C" void kernel_launch(void* const* d_in, const int* in_sizes, int n_in,
                              void* d_out, int out_size, void* d_ws, size_t ws_size,
                              hipStream_t stream)
{
    const float* h   = (const float*)d_in[0];
    const int*   src = (const int*)d_in[1];
    const int*   dst = (const int*)d_in[2];
    const int*   rel = (const int*)d_in[3];
    const int*   gid = (const int*)d_in[4];
    const float* W1  = (const float*)d_in[5];
    const float* Ws1 = (const float*)d_in[6];
    const float* b1  = (const float*)d_in[7];
    const float* W2  = (const float*)d_in[8];
    const float* Ws2 = (const float*)d_in[9];
    const float* b2  = (const float*)d_in[10];
    const float* Wfc = (const float*)d_in[11];
    const float* bfc = (const float*)d_in[12];
    const float* Wc  = (const float*)d_in[13];
    const float* bc  = (const float*)d_in[14];
    float* out = (float*)d_out;

    char* ws = (char*)d_ws;
    unsigned char* mark = (unsigned char*)(ws + WS_MARK);
    int*   histD = (int*)(ws + WS_HISTD);
    float* hgsum = (float*)(ws + WS_HG);
    int*   cnt   = (int*)(ws + WS_CNT);
    int*   srcOf = (int*)(ws + WS_SRCOF);
    int*   offsD = (int*)(ws + WS_OFFSD);
    int*   curD  = (int*)(ws + WS_CURD);
    int*   partD = (int*)(ws + WS_PARTD);
    int*   partP = (int*)(ws + WS_PARTP);
    int*   blkB  = (int*)(ws + WS_BLKB);
    int*   relB  = (int*)(ws + WS_RELB);
    int*   cidMap= (int*)(ws + WS_CIDMAP);
    unsigned int* recs = (unsigned int*)(ws + WS_RECS);
    unsigned short* x1  = (unsigned short*)(ws + WS_X1);
    unsigned short* x2  = (unsigned short*)(ws + WS_X2);
    unsigned short* agg = (unsigned short*)(ws + WS_AGG);
    unsigned short* Wb  = (unsigned short*)(ws + WS_WB);
    unsigned short* T   = (unsigned short*)(ws + WS_T);

    // cap phaseA grid by T capacity (host constant -> capture-safe)
    int gridA = MAXBLK_A;
    if (ws_size > (size_t)WS_T) {
        long long capRows = (long long)((ws_size - WS_T) / 256);
        long long capBlk = capRows / 64;
        if (capBlk < gridA) gridA = (int)capBlk;
    }

    hipMemsetAsync(mark, 0, MEMSET_SZ, stream);    // mark+histD+hg+cnt+srcOf

    k_convXW<<<XW_TOTAL / 256, 256, 0, stream>>>(h, x1, W1, Ws1, W2, Ws2, Wb);
    k_hist2<<<(N_EDGES + 255) / 256, 256, 0, stream>>>(src, dst, rel, mark, histD);

    k_scanA<<<NBLK_PD, 256, 0, stream>>>(histD, partD);
    k_scanB<<<1, 256, 0, stream>>>(partD, offsD + NBINS_D);
    k_scanC<<<NBLK_PD, 256, 0, stream>>>(histD, partD, offsD, curD);

    k_scanPA<<<NBLK_PP, 256, 0, stream>>>((const unsigned int*)mark, partP);
    k_scanPB<<<1, 1024, 0, stream>>>(partP, blkB, relB);
    k_scanPC<<<NBLK_PP, 256, 0, stream>>>((const unsigned int*)mark, blkB, cidMap, srcOf);

    k_scatterK<<<(N_EDGES + 255) / 256, 256, 0, stream>>>(src, dst, rel, cidMap, curD, recs);

    k_phaseA<<<gridA, 256, 0, stream>>>(x1, Wb, srcOf, relB, T);
    k_phaseB<<<N_PAD / 32, 256, 0, stream>>>(T, recs, offsD, relB, b1, x2, 1);
    k_phaseA<<<gridA, 256, 0, stream>>>(x2, Wb + 17 * 16384, srcOf, relB, T);
    k_phaseB<<<N_PAD / 32, 256, 0, stream>>>(T, recs, offsD, relB, b2, agg, 0);

    k_pool<<<(N_PAD + POOL_CH - 1) / POOL_CH, 128, 0, stream>>>(agg, gid, hgsum, cnt);
    k_head<<<N_GRAPHS, 256, 0, stream>>>(hgsum, cnt, Wfc, bfc, Wc, bc, out);
}

// Round 14
// 437.036 us; speedup vs baseline: 4.0351x; 1.0410x over previous
//
#include <hip/hip_runtime.h>
#include <hip/hip_bf16.h>

#define N_NODES   50000
#define N_PAD     50048                 // ceil64
#define N_EDGES   800000
#define N_REL     16
#define N_GRAPHS  64
#define DIM       128
#define FC_DIM    256
#define N_CLASSES 16

#define SB        50176                 // src bins per rel (49*1024)
#define NBINS_P   (16 * SB)             // 802816
#define NBLK_PP   784
#define NCOARSE   782                   // dst>>6 bins
#define NCH       98                    // edge chunks
#define CHSZ      8192
#define POOL_CH   64
#define MAXBLK_A  13294

// ---- ws layout (bytes, 256-aligned) ----
#define WS_MARK   0                     // 802816  } contiguous
#define WS_HG     802816                // 32768   } memset
#define WS_CNT    835584                // 256     } region
#define WS_SRCOF  835840                // 3203072 } (pads must be 0)
#define MEMSET_SZ 4038912
#define WS_BLKH   4038912               // 98*782*4 = 306544 -> 306688
#define WS_COFS   4345600               // 3328
#define WS_PARTP  4348928               // 3328
#define WS_BLKB   4352256               // 3328
#define WS_RELB   4355584               // 256
#define WS_CIDMAP 4355840               // 3211264
#define WS_RTMP   7567104               // 3200000
#define WS_RECS   10767104              // 3200000
#define WS_OFFSD  13967104              // 200448
#define WS_X1     14167552              // 12812288
#define WS_X2     26979840              // 12812288
#define WS_AGG    39792128              // 12812288 (bf16)
#define WS_WB     52604416              // 1114112
#define WS_T      53718528              // + rows*256B (actual ~142MB)

#define XW_TOTAL  (N_PAD * DIM + 2 * 17 * 16384)

typedef __attribute__((ext_vector_type(8))) short bf16x8;
typedef __attribute__((ext_vector_type(4))) float f32x4;

__device__ __forceinline__ void atomAddF(float* p, float v) {
#if defined(__gfx90a__) || defined(__gfx942__) || defined(__gfx950__)
    unsafeAtomicAdd(p, v);
#else
    atomicAdd(p, v);
#endif
}

__device__ __forceinline__ float bf2f(unsigned int u) {
    union { float f; unsigned int i; } x; x.i = u << 16; return x.f;
}
__device__ __forceinline__ unsigned short f2bf(float f) {
    union { float f; unsigned int u; } x; x.f = f;
    unsigned int r = x.u + 0x7fff + ((x.u >> 16) & 1);
    return (unsigned short)(r >> 16);
}
__device__ __forceinline__ void accum8(float* qa, uint4 u) {
    qa[0] += bf2f(u.x & 0xffff); qa[1] += bf2f(u.x >> 16);
    qa[2] += bf2f(u.y & 0xffff); qa[3] += bf2f(u.y >> 16);
    qa[4] += bf2f(u.z & 0xffff); qa[5] += bf2f(u.z >> 16);
    qa[6] += bf2f(u.w & 0xffff); qa[7] += bf2f(u.w >> 16);
}
__device__ __forceinline__ void pack16(const float* qa, unsigned short* dst) {
    #pragma unroll
    for (int j = 0; j < 2; ++j) {
        uint4 w;
        w.x = ((unsigned int)f2bf(qa[j*8+1]) << 16) | f2bf(qa[j*8+0]);
        w.y = ((unsigned int)f2bf(qa[j*8+3]) << 16) | f2bf(qa[j*8+2]);
        w.z = ((unsigned int)f2bf(qa[j*8+5]) << 16) | f2bf(qa[j*8+4]);
        w.w = ((unsigned int)f2bf(qa[j*8+7]) << 16) | f2bf(qa[j*8+6]);
        ((uint4*)dst)[j] = w;
    }
}

// merged convX + convW
__global__ void k_convXW(const float* __restrict__ h, unsigned short* __restrict__ x1,
                         const float* __restrict__ W1, const float* __restrict__ Ws1,
                         const float* __restrict__ W2, const float* __restrict__ Ws2,
                         unsigned short* __restrict__ Wb) {
    int id = blockIdx.x * blockDim.x + threadIdx.x;
    if (id < N_PAD * DIM) {
        int v = id >> 7;
        x1[id] = (v < N_NODES) ? f2bf(h[id]) : (unsigned short)0;
    } else {
        int t = id - N_PAD * DIM;
        int l = t / 278528, rem = t % 278528;
        int r = rem >> 14, rr = rem & 16383;
        int n = rr >> 7, k = rr & 127;
        const float* W  = l ? W2 : W1;
        const float* Ws = l ? Ws2 : Ws1;
        float v = (r < 16) ? W[r * 16384 + k * 128 + n] : Ws[k * 128 + n];
        Wb[t] = f2bf(v);
    }
}

// ---- sort pass 1a: per-chunk LDS coarse histogram + dedup marks (NO global atomics) ----
__global__ __launch_bounds__(256) void k_h1(
    const int* __restrict__ src, const int* __restrict__ dst, const int* __restrict__ rel,
    unsigned char* __restrict__ mark, int* __restrict__ blockHist)
{
    __shared__ int hl[NCOARSE];
    int b = blockIdx.x, t = threadIdx.x;
    for (int i = t; i < NCOARSE; i += 256) hl[i] = 0;
    __syncthreads();
    int e0 = b * CHSZ;
    int eend = min(e0 + CHSZ, N_EDGES);
    for (int e = e0 + t; e < eend; e += 256) {
        int d = dst[e];
        mark[rel[e] * SB + src[e]] = 1;
        atomicAdd(&hl[d >> 6], 1);                       // LDS atomic
    }
    __syncthreads();
    for (int i = t; i < NCOARSE; i += 256) blockHist[b * NCOARSE + i] = hl[i];
}

// ---- coarse scan: blockHist -> absolute bases (in place) + coarseOffs ----
__global__ void k_cscan(int* __restrict__ blockHist, int* __restrict__ coarseOffs) {
    __shared__ int s1[1024], s2[1024];
    int t = threadIdx.x;
    int tot = 0;
    if (t < NCOARSE) {
        int run = 0;
        for (int b = 0; b < NCH; ++b) {
            int v = blockHist[b * NCOARSE + t];
            blockHist[b * NCOARSE + t] = run;
            run += v;
        }
        tot = run;
    }
    s1[t] = tot; __syncthreads();
    int* cur = s1; int* nxt = s2;
    for (int o = 1; o < 1024; o <<= 1) {
        nxt[t] = cur[t] + ((t >= o) ? cur[t - o] : 0);
        __syncthreads();
        int* tmp = cur; cur = nxt; nxt = tmp;
    }
    if (t < NCOARSE) {
        int base = cur[t] - tot;                         // exclusive
        coarseOffs[t] = base;
        for (int b = 0; b < NCH; ++b) blockHist[b * NCOARSE + t] += base;
    }
    if (t == NCOARSE) coarseOffs[NCOARSE] = cur[NCOARSE - 1];
}

// ---- pair dedup (unchanged from r13) ----
__global__ void k_scanPA(const unsigned int* __restrict__ markU, int* __restrict__ partP) {
    __shared__ int red[256];
    int b = blockIdx.x, t = threadIdx.x;
    unsigned int u = markU[b * 256 + t];
    red[t] = (int)((u & 1) + ((u >> 8) & 1) + ((u >> 16) & 1) + ((u >> 24) & 1));
    __syncthreads();
    for (int o = 128; o > 0; o >>= 1) {
        if (t < o) red[t] += red[t + o];
        __syncthreads();
    }
    if (t == 0) partP[b] = red[0];
}

__global__ void k_scanPB(const int* __restrict__ partP, int* __restrict__ blkB,
                         int* __restrict__ relB) {
    __shared__ int s1[784], s2[784];
    __shared__ int tot[16], rbase[17];
    int t = threadIdx.x;                                 // blockDim = 1024
    int rel = t / 49, pos = t - rel * 49;
    int v = (t < 784) ? partP[t] : 0;
    if (t < 784) s1[t] = v;
    __syncthreads();
    int* cur = s1; int* nxt = s2;
    for (int o = 1; o < 64; o <<= 1) {
        if (t < 784) nxt[t] = cur[t] + ((pos >= o) ? cur[t - o] : 0);
        __syncthreads();
        int* tmp = cur; cur = nxt; nxt = tmp;
    }
    if (t < 784 && pos == 48) tot[rel] = cur[t];
    __syncthreads();
    if (t == 0) {
        int base = 0;
        for (int r = 0; r < 16; ++r) { rbase[r] = base; base += (tot[r] + 63) & ~63; }
        rbase[16] = base;
    }
    __syncthreads();
    if (t < 784) blkB[t] = rbase[rel] + cur[t] - v;
    if (t < 17)  relB[t] = rbase[t];
}

__global__ void k_scanPC(const unsigned int* __restrict__ markU, const int* __restrict__ blkB,
                         int* __restrict__ cidMap, int* __restrict__ srcOf) {
    __shared__ int s1[256], s2[256];
    int b = blockIdx.x, t = threadIdx.x;
    unsigned int u = markU[b * 256 + t];
    int f0 = (int)(u & 1), f1 = (int)((u >> 8) & 1);
    int f2 = (int)((u >> 16) & 1), f3 = (int)((u >> 24) & 1);
    int sum = f0 + f1 + f2 + f3;
    s1[t] = sum; __syncthreads();
    int* cur = s1; int* nxt = s2;
    for (int o = 1; o < 256; o <<= 1) {
        nxt[t] = cur[t] + ((t >= o) ? cur[t - o] : 0);
        __syncthreads();
        int* tmp = cur; cur = nxt; nxt = tmp;
    }
    int cid = blkB[b] + cur[t] - sum;
    int rel = b / 49;
    int key0 = b * 1024 + t * 4;
    int srcBase = key0 - rel * SB;
    if (f0) { cidMap[key0]     = cid; srcOf[cid] = srcBase;     cid++; }
    if (f1) { cidMap[key0 + 1] = cid; srcOf[cid] = srcBase + 1; cid++; }
    if (f2) { cidMap[key0 + 2] = cid; srcOf[cid] = srcBase + 2; cid++; }
    if (f3) { cidMap[key0 + 3] = cid; srcOf[cid] = srcBase + 3; cid++; }
}

// ---- sort pass 1b: scatter to coarse segments (LDS ranks, plain writes) ----
__global__ __launch_bounds__(256) void k_scat1(
    const int* __restrict__ src, const int* __restrict__ dst, const int* __restrict__ rel,
    const int* __restrict__ cidMap, const int* __restrict__ blockHist,
    unsigned int* __restrict__ rtmp)
{
    __shared__ int baseL[NCOARSE];
    __shared__ int hl[NCOARSE];
    int b = blockIdx.x, t = threadIdx.x;
    for (int i = t; i < NCOARSE; i += 256) { baseL[i] = blockHist[b * NCOARSE + i]; hl[i] = 0; }
    __syncthreads();
    int e0 = b * CHSZ;
    int eend = min(e0 + CHSZ, N_EDGES);
    for (int e = e0 + t; e < eend; e += 256) {
        int d = dst[e];
        int cid = cidMap[rel[e] * SB + src[e]];
        int c = d >> 6;
        int rank = atomicAdd(&hl[c], 1);                 // LDS atomic
        rtmp[baseL[c] + rank] = ((unsigned int)cid << 6) | (unsigned int)(d & 63);
    }
}

// ---- sort pass 2: per coarse bin, final 64-way local sort + offsD ----
__global__ __launch_bounds__(256) void k_p2(
    const unsigned int* __restrict__ rtmp, const int* __restrict__ coarseOffs,
    unsigned int* __restrict__ recs, int* __restrict__ offsD)
{
    __shared__ int cntL[64], exclL[65], cur2[64];
    int i = blockIdx.x, t = threadIdx.x;
    int segB = coarseOffs[i], segE = coarseOffs[i + 1];
    if (t < 64) { cntL[t] = 0; cur2[t] = 0; }
    __syncthreads();
    for (int e = segB + t; e < segE; e += 256)
        atomicAdd(&cntL[rtmp[e] & 63u], 1);
    __syncthreads();
    if (t == 0) {
        int run = segB;
        #pragma unroll
        for (int d = 0; d < 64; ++d) { exclL[d] = run; run += cntL[d]; }
        exclL[64] = run;
    }
    __syncthreads();
    if (t < 64) offsD[i * 64 + t] = exclL[t];
    if (t == 64) offsD[i * 64 + 64] = exclL[64];
    for (int e = segB + t; e < segE; e += 256) {
        unsigned int r = rtmp[e];
        int d = (int)(r & 63u);
        int rank = atomicAdd(&cur2[d], 1);               // LDS atomic
        recs[exclL[d] + rank] = r >> 6;
    }
}

// ---- Phase A: gather-GEMM over compact rows (unchanged r13) ----
__global__ __launch_bounds__(256) void k_phaseA(
    const unsigned short* __restrict__ x, const unsigned short* __restrict__ Wb,
    const int* __restrict__ srcOf, const int* __restrict__ relB,
    unsigned short* __restrict__ T)
{
    __shared__ unsigned short Xs[64 * 136];
    __shared__ unsigned short Cs[64 * 136];
    __shared__ int sSrc[64];
    __shared__ int sRB[17];

    int tid = threadIdx.x;
    if (tid < 17) sRB[tid] = relB[tid];
    __syncthreads();

    int row0 = blockIdx.x * 64;
    int rtot = sRB[16];
    if (row0 >= rtot + N_PAD) return;

    int r = 16;
    #pragma unroll
    for (int i = 0; i < 16; ++i)
        if (row0 < sRB[i + 1]) { r = i; break; }

    if (tid < 64) sSrc[tid] = (r == 16) ? (row0 - rtot + tid) : srcOf[row0 + tid];
    __syncthreads();

    {
        int row = tid >> 2, c0 = tid & 3;
        const uint4* xp = (const uint4*)(x + (size_t)sSrc[row] * DIM);
        uint4* lp = (uint4*)(&Xs[row * 136]);
        #pragma unroll
        for (int i = 0; i < 4; ++i) lp[c0 + 4 * i] = xp[c0 + 4 * i];
    }
    __syncthreads();

    int w = tid >> 6, l = tid & 63;
    int nl = l & 15, q = l >> 4;

    bf16x8 Bf[2][4];
    const unsigned short* wr = Wb + r * 16384;
    #pragma unroll
    for (int nt = 0; nt < 2; ++nt) {
        int n = w * 32 + nt * 16 + nl;
        #pragma unroll
        for (int kc = 0; kc < 4; ++kc)
            Bf[nt][kc] = *(const bf16x8*)(wr + n * 128 + kc * 32 + q * 8);
    }
    #pragma unroll
    for (int m = 0; m < 4; ++m) {
        f32x4 a0 = {0.f,0.f,0.f,0.f}, a1 = {0.f,0.f,0.f,0.f};
        #pragma unroll
        for (int kc = 0; kc < 4; ++kc) {
            bf16x8 a = *(const bf16x8*)(&Xs[(m * 16 + nl) * 136 + kc * 32 + q * 8]);
            a0 = __builtin_amdgcn_mfma_f32_16x16x32_bf16(a, Bf[0][kc], a0, 0, 0, 0);
            a1 = __builtin_amdgcn_mfma_f32_16x16x32_bf16(a, Bf[1][kc], a1, 0, 0, 0);
        }
        int col = w * 32 + nl;
        #pragma unroll
        for (int reg = 0; reg < 4; ++reg) {
            int row = m * 16 + q * 4 + reg;
            Cs[row * 136 + col]      = f2bf(a0[reg]);
            Cs[row * 136 + col + 16] = f2bf(a1[reg]);
        }
    }
    __syncthreads();
    {
        unsigned short* Tb = T + (size_t)row0 * DIM;
        #pragma unroll
        for (int it = 0; it < 4; ++it) {
            int c = tid + it * 256;
            int row = c >> 4, k8 = c & 15;
            uint4 vv = *(const uint4*)(&Cs[row * 136 + k8 * 8]);
            *(uint4*)(Tb + row * DIM + k8 * 8) = vv;
        }
    }
}

// ---- Phase B: unchanged r13 ----
__global__ __launch_bounds__(256) void k_phaseB(
    const unsigned short* __restrict__ T, const unsigned int* __restrict__ recs,
    const int* __restrict__ offsD, const int* __restrict__ relB,
    const float* __restrict__ bias,
    unsigned short* __restrict__ aggOut, int relu)
{
    __shared__ int sOffs[33];
    __shared__ float sBias[128];
    __shared__ int sSelf;
    int tid = threadIdx.x;
    int v0 = blockIdx.x * 32;
    if (tid < 33) sOffs[tid] = offsD[v0 + tid];
    if (tid == 40) sSelf = relB[16];
    if (tid >= 64 && tid < 96) ((float4*)sBias)[tid - 64] = ((const float4*)bias)[tid - 64];
    __syncthreads();

    int g = tid >> 3, s = tid & 7;
    int dst = v0 + g;
    float qa[16];
    #pragma unroll
    for (int i = 0; i < 16; ++i) qa[i] = sBias[s * 16 + i];

    int beg = sOffs[g], end = sOffs[g + 1];
    int e = beg;
    for (; e + 3 < end; e += 4) {
        unsigned int c0 = recs[e], c1 = recs[e+1], c2 = recs[e+2], c3 = recs[e+3];
        const uint4* t0 = (const uint4*)(T + (size_t)c0 * DIM + s * 16);
        const uint4* t1 = (const uint4*)(T + (size_t)c1 * DIM + s * 16);
        const uint4* t2 = (const uint4*)(T + (size_t)c2 * DIM + s * 16);
        const uint4* t3 = (const uint4*)(T + (size_t)c3 * DIM + s * 16);
        uint4 a0 = t0[0], a1 = t0[1], b0 = t1[0], b1 = t1[1];
        uint4 cc0 = t2[0], cc1 = t2[1], d0 = t3[0], d1 = t3[1];
        accum8(qa, a0); accum8(qa + 8, a1);
        accum8(qa, b0); accum8(qa + 8, b1);
        accum8(qa, cc0); accum8(qa + 8, cc1);
        accum8(qa, d0); accum8(qa + 8, d1);
    }
    for (; e < end; ++e) {
        unsigned int c = recs[e];
        const uint4* tp = (const uint4*)(T + (size_t)c * DIM + s * 16);
        uint4 u0 = tp[0], u1 = tp[1];
        accum8(qa, u0); accum8(qa + 8, u1);
    }
    {
        const uint4* tp = (const uint4*)(T + (size_t)(sSelf + dst) * DIM + s * 16);
        uint4 u0 = tp[0], u1 = tp[1];
        accum8(qa, u0); accum8(qa + 8, u1);
    }

    if (relu) {
        #pragma unroll
        for (int i = 0; i < 16; ++i) qa[i] = fmaxf(qa[i], 0.f);
    }
    pack16(qa, aggOut + (size_t)dst * DIM + s * 16);
}

__global__ void k_pool(const unsigned short* __restrict__ agg2, const int* __restrict__ gids,
                       float* __restrict__ hg_sum, int* __restrict__ cnt)
{
    int d  = threadIdx.x;
    int n0 = blockIdx.x * POOL_CH;
    int nend = min(n0 + POOL_CH, N_NODES);
    if (n0 >= N_NODES) return;
    int curg = gids[n0];
    float run = 0.f;
    for (int n = n0; n < nend; ++n) {
        int g = gids[n];
        if (g != curg) { atomAddF(&hg_sum[curg*DIM + d], run); run = 0.f; curg = g; }
        run += fmaxf(bf2f((unsigned int)agg2[n*DIM + d]), 0.f);
    }
    atomAddF(&hg_sum[curg*DIM + d], run);
    if (d == 0) {
        int cg = gids[n0]; int rl = 0;
        for (int n = n0; n < nend; ++n) {
            int g = gids[n];
            if (g != cg) { atomicAdd(&cnt[cg], rl); rl = 0; cg = g; }
            rl++;
        }
        atomicAdd(&cnt[cg], rl);
    }
}

__global__ __launch_bounds__(256) void k_head(
    const float* __restrict__ hg_sum, const int* __restrict__ cnt,
    const float* __restrict__ Wfc, const float* __restrict__ bfc,
    const float* __restrict__ Wc, const float* __restrict__ bc,
    float* __restrict__ out)
{
    int g = blockIdx.x, t = threadIdx.x;
    __shared__ float hgl[DIM];
    __shared__ float fcl[FC_DIM];
    __shared__ float lg[N_CLASSES];
    if (t < DIM) {
        float c = (float)max(cnt[g], 1);
        hgl[t] = hg_sum[g*DIM + t] / c;
    }
    __syncthreads();
    {
        float sv = bfc[t];
        #pragma unroll 4
        for (int k = 0; k < DIM; ++k) sv += hgl[k] * Wfc[k*FC_DIM + t];
        fcl[t] = fmaxf(sv, 0.f);
    }
    __syncthreads();
    if (t < N_CLASSES) {
        float lgt = bc[t];
        #pragma unroll 4
        for (int k = 0; k < FC_DIM; ++k) lgt += fcl[k] * Wc[k*N_CLASSES + t];
        lg[t] = lgt;
    }
    __syncthreads();
    if (t < N_CLASSES) {
        float m = lg[0];
        #pragma unroll
        for (int c = 1; c < N_CLASSES; ++c) m = fmaxf(m, lg[c]);
        float sden = 0.f;
        #pragma unroll
        for (int c = 0; c < N_CLASSES; ++c) sden += expf(lg[c] - m);
        out[g*N_CLASSES + t] = expf(lg[t] - m) / sden;
    }
}

extern "C" void kernel_launch(void* const* d_in, const int* in_sizes, int n_in,
                              void* d_out, int out_size, void* d_ws, size_t ws_size,
                              hipStream_t stream)
{
    const float* h   = (const float*)d_in[0];
    const int*   src = (const int*)d_in[1];
    const int*   dst = (const int*)d_in[2];
    const int*   rel = (const int*)d_in[3];
    const int*   gid = (const int*)d_in[4];
    const float* W1  = (const float*)d_in[5];
    const float* Ws1 = (const float*)d_in[6];
    const float* b1  = (const float*)d_in[7];
    const float* W2  = (const float*)d_in[8];
    const float* Ws2 = (const float*)d_in[9];
    const float* b2  = (const float*)d_in[10];
    const float* Wfc = (const float*)d_in[11];
    const float* bfc = (const float*)d_in[12];
    const float* Wc  = (const float*)d_in[13];
    const float* bc  = (const float*)d_in[14];
    float* out = (float*)d_out;

    char* ws = (char*)d_ws;
    unsigned char* mark = (unsigned char*)(ws + WS_MARK);
    float* hgsum = (float*)(ws + WS_HG);
    int*   cnt   = (int*)(ws + WS_CNT);
    int*   srcOf = (int*)(ws + WS_SRCOF);
    int*   blkH  = (int*)(ws + WS_BLKH);
    int*   cOffs = (int*)(ws + WS_COFS);
    int*   partP = (int*)(ws + WS_PARTP);
    int*   blkB  = (int*)(ws + WS_BLKB);
    int*   relB  = (int*)(ws + WS_RELB);
    int*   cidMap= (int*)(ws + WS_CIDMAP);
    unsigned int* rtmp = (unsigned int*)(ws + WS_RTMP);
    unsigned int* recs = (unsigned int*)(ws + WS_RECS);
    int*   offsD = (int*)(ws + WS_OFFSD);
    unsigned short* x1  = (unsigned short*)(ws + WS_X1);
    unsigned short* x2  = (unsigned short*)(ws + WS_X2);
    unsigned short* agg = (unsigned short*)(ws + WS_AGG);
    unsigned short* Wb  = (unsigned short*)(ws + WS_WB);
    unsigned short* T   = (unsigned short*)(ws + WS_T);

    int gridA = MAXBLK_A;
    if (ws_size > (size_t)WS_T) {
        long long capRows = (long long)((ws_size - WS_T) / 256);
        long long capBlk = capRows / 64;
        if (capBlk < gridA) gridA = (int)capBlk;
    }

    hipMemsetAsync(mark, 0, MEMSET_SZ, stream);    // mark+hg+cnt+srcOf

    k_convXW<<<XW_TOTAL / 256, 256, 0, stream>>>(h, x1, W1, Ws1, W2, Ws2, Wb);
    k_h1<<<NCH, 256, 0, stream>>>(src, dst, rel, mark, blkH);

    k_cscan<<<1, 1024, 0, stream>>>(blkH, cOffs);
    k_scanPA<<<NBLK_PP, 256, 0, stream>>>((const unsigned int*)mark, partP);
    k_scanPB<<<1, 1024, 0, stream>>>(partP, blkB, relB);
    k_scanPC<<<NBLK_PP, 256, 0, stream>>>((const unsigned int*)mark, blkB, cidMap, srcOf);

    k_scat1<<<NCH, 256, 0, stream>>>(src, dst, rel, cidMap, blkH, rtmp);
    k_p2<<<NCOARSE, 256, 0, stream>>>(rtmp, cOffs, recs, offsD);

    k_phaseA<<<gridA, 256, 0, stream>>>(x1, Wb, srcOf, relB, T);
    k_phaseB<<<N_PAD / 32, 256, 0, stream>>>(T, recs, offsD, relB, b1, x2, 1);
    k_phaseA<<<gridA, 256, 0, stream>>>(x2, Wb + 17 * 16384, srcOf, relB, T);
    k_phaseB<<<N_PAD / 32, 256, 0, stream>>>(T, recs, offsD, relB, b2, agg, 0);

    k_pool<<<(N_PAD + POOL_CH - 1) / POOL_CH, 128, 0, stream>>>(agg, gid, hgsum, cnt);
    k_head<<<N_GRAPHS, 256, 0, stream>>>(hgsum, cnt, Wfc, bfc, Wc, bc, out);
}